// Round 1
// baseline (878.224 us; speedup 1.0000x reference)
//
#include <hip/hip_runtime.h>
#include <math.h>

#define Bb 4
#define Ss 512
#define Dd 512
#define Hh 2048
#define Ee 8
#define TOKENS 2048
#define CAP 2048

// ---------------- ws layout (bytes) ----------------
// 0      : int   cnt[8]
// 32     : int   offs[8]
// 64     : float imp[8]
// 96     : float zsum
// 100    : float esum
// 128    : float M1[512*8]     (16384 B)
// 16512  : float qv[8]
// 16544  : float cb[8]
// 16640  : int   list[8*2048]  (65536 B)
// 82176  : float glist[8*2048] (65536 B)
// 147712 : float hbuf[4096*2048]  (32 MiB)
// total ~33.7 MB

__device__ __forceinline__ float wred(float v) {
#pragma unroll
  for (int o = 32; o > 0; o >>= 1) v += __shfl_down(v, o);
  return v;
}

__device__ __forceinline__ float block_sum(float v, float* s4, int tid) {
  v = wred(v);
  __syncthreads();
  if ((tid & 63) == 0) s4[tid >> 6] = v;
  __syncthreads();
  return s4[0] + s4[1] + s4[2] + s4[3];
}

__device__ __forceinline__ float gelu_f(float v) {
  return 0.5f * v * (1.0f + erff(v * 0.7071067811865475f));
}

// ------------------------------------------------------------------
// Precompute M1 = ctx_W @ rtr_W (512x8), qv = qual_W@rtr_W, cb = (ctx_b+qual_b)@rtr_W + rtr_b
// grid: 513 blocks x 64 threads
// ------------------------------------------------------------------
__global__ __launch_bounds__(64) void k_precomp(
    const float* __restrict__ ctx_W, const float* __restrict__ rtr_W,
    const float* __restrict__ rtr_b, const float* __restrict__ qual_W,
    const float* __restrict__ qual_b, const float* __restrict__ ctx_b,
    float* __restrict__ M1, float* __restrict__ qv, float* __restrict__ cb) {
  int d = blockIdx.x;
  int lane = threadIdx.x;
  if (d < Dd) {
    float acc[Ee] = {0.f, 0.f, 0.f, 0.f, 0.f, 0.f, 0.f, 0.f};
    for (int k = lane; k < Dd; k += 64) {
      float cw = ctx_W[d * Dd + k];
      const float* r = rtr_W + k * Ee;
#pragma unroll
      for (int e = 0; e < Ee; e++) acc[e] += cw * r[e];
    }
#pragma unroll
    for (int e = 0; e < Ee; e++) acc[e] = wred(acc[e]);
    if (lane == 0) {
#pragma unroll
      for (int e = 0; e < Ee; e++) M1[d * Ee + e] = acc[e];
    }
  } else {
    float aq[Ee] = {0.f, 0.f, 0.f, 0.f, 0.f, 0.f, 0.f, 0.f};
    float ab[Ee] = {0.f, 0.f, 0.f, 0.f, 0.f, 0.f, 0.f, 0.f};
    for (int k = lane; k < Dd; k += 64) {
      float qw = qual_W[k];
      float bb = ctx_b[k] + qual_b[k];
      const float* r = rtr_W + k * Ee;
#pragma unroll
      for (int e = 0; e < Ee; e++) {
        aq[e] += qw * r[e];
        ab[e] += bb * r[e];
      }
    }
#pragma unroll
    for (int e = 0; e < Ee; e++) {
      aq[e] = wred(aq[e]);
      ab[e] = wred(ab[e]);
    }
    if (lane == 0) {
#pragma unroll
      for (int e = 0; e < Ee; e++) {
        qv[e] = aq[e];
        cb[e] = ab[e] + rtr_b[e];
      }
    }
  }
}

// ------------------------------------------------------------------
// Router: one block (256 thr) per token.
// logits = (LN(x)@rtr_W + LN(ctx)@M1 + quality[b]*qv + cb) * invT
// top-2, gates, stats, per-expert token lists.
// ------------------------------------------------------------------
__global__ __launch_bounds__(256) void k_router(
    const float* __restrict__ x, const float* __restrict__ ctx,
    const float* __restrict__ quality, const float* __restrict__ rn_g,
    const float* __restrict__ rn_b, const float* __restrict__ cn_g,
    const float* __restrict__ cn_b, const float* __restrict__ rtr_W,
    const float* __restrict__ M1, const float* __restrict__ qv,
    const float* __restrict__ cb, const float* __restrict__ temperature,
    int* __restrict__ cnt, int* __restrict__ list, float* __restrict__ glist,
    float* __restrict__ imp, float* __restrict__ zsum, float* __restrict__ esum) {
  int t = blockIdx.x;
  int tid = threadIdx.x;
  __shared__ float s4[4];
  __shared__ float slg[4][Ee];

  const float* xr = x + (size_t)t * Dd;
  const float* cr = ctx + (size_t)t * Dd;
  float x0 = xr[tid], x1 = xr[tid + 256];
  float c0 = cr[tid], c1 = cr[tid + 256];

  float sx = block_sum(x0 + x1, s4, tid);
  float sc = block_sum(c0 + c1, s4, tid);
  float mx = sx * (1.f / Dd), mc = sc * (1.f / Dd);
  float vx = block_sum((x0 - mx) * (x0 - mx) + (x1 - mx) * (x1 - mx), s4, tid);
  float vc = block_sum((c0 - mc) * (c0 - mc) + (c1 - mc) * (c1 - mc), s4, tid);
  float rsx = rsqrtf(vx * (1.f / Dd) + 1e-5f);
  float rsc = rsqrtf(vc * (1.f / Dd) + 1e-5f);

  float lg[Ee] = {0.f, 0.f, 0.f, 0.f, 0.f, 0.f, 0.f, 0.f};
  {
    int d = tid;
    float xn = (x0 - mx) * rsx * rn_g[d] + rn_b[d];
    float cn = (c0 - mc) * rsc * cn_g[d] + cn_b[d];
    const float* rw = rtr_W + d * Ee;
    const float* m1 = M1 + d * Ee;
#pragma unroll
    for (int e = 0; e < Ee; e++) lg[e] += xn * rw[e] + cn * m1[e];
    d = tid + 256;
    xn = (x1 - mx) * rsx * rn_g[d] + rn_b[d];
    cn = (c1 - mc) * rsc * cn_g[d] + cn_b[d];
    rw = rtr_W + d * Ee;
    m1 = M1 + d * Ee;
#pragma unroll
    for (int e = 0; e < Ee; e++) lg[e] += xn * rw[e] + cn * m1[e];
  }
#pragma unroll
  for (int e = 0; e < Ee; e++) lg[e] = wred(lg[e]);
  if ((tid & 63) == 0) {
#pragma unroll
    for (int e = 0; e < Ee; e++) slg[tid >> 6][e] = lg[e];
  }
  __syncthreads();

  if (tid == 0) {
    float invT = 1.f / fmaxf(temperature[0], 0.25f);
    int b = t / Ss;
    float q = quality[b];
    float L[Ee];
#pragma unroll
    for (int e = 0; e < Ee; e++)
      L[e] = (slg[0][e] + slg[1][e] + slg[2][e] + slg[3][e] + q * qv[e] + cb[e]) * invT;

    // top-2, ties -> lowest index (matches lax.top_k)
    int i0 = 0;
#pragma unroll
    for (int e = 1; e < Ee; e++)
      if (L[e] > L[i0]) i0 = e;
    int i1 = (i0 == 0) ? 1 : 0;
#pragma unroll
    for (int e = 0; e < Ee; e++)
      if (e != i0 && L[e] > L[i1]) i1 = e;

    float e1 = __expf(L[i1] - L[i0]);
    float g0 = 1.f / (1.f + e1);
    float g1 = e1 / (1.f + e1);

    // full softmax stats
    float m = L[i0];
    float p[Ee];
    float sum = 0.f;
#pragma unroll
    for (int e = 0; e < Ee; e++) {
      p[e] = __expf(L[e] - m);
      sum += p[e];
    }
    float lse = m + __logf(sum);
    float inv = 1.f / sum;
    float ent = 0.f;
#pragma unroll
    for (int e = 0; e < Ee; e++) {
      p[e] *= inv;
      ent -= p[e] * __logf(fmaxf(p[e], 1e-9f));
      atomicAdd(&imp[e], p[e]);
    }
    atomicAdd(zsum, lse * lse);
    atomicAdd(esum, ent);

    int p0 = atomicAdd(&cnt[i0], 1);
    list[i0 * CAP + p0] = t;
    glist[i0 * CAP + p0] = g0;
    int p1 = atomicAdd(&cnt[i1], 1);
    list[i1 * CAP + p1] = t;
    glist[i1 * CAP + p1] = g1;
  }
}

__global__ void k_offs(const int* __restrict__ cnt, int* __restrict__ offs) {
  if (threadIdx.x == 0 && blockIdx.x == 0) {
    int s = 0;
#pragma unroll
    for (int e = 0; e < Ee; e++) {
      offs[e] = s;
      s += cnt[e];
    }
  }
}

// ------------------------------------------------------------------
// GEMM1: for expert e, gathered X rows (ne x 512) @ W1[e] (512 x 2048) + b1 -> gelu -> hbuf
// grid: 8 * 32 * 32 = 8192 blocks x 256 thr, 64x64 tile, 4x4/thread, KT=16
// ------------------------------------------------------------------
__global__ __launch_bounds__(256) void k_gemm1(
    const float* __restrict__ x, const float* __restrict__ W1,
    const float* __restrict__ b1, const int* __restrict__ cnt,
    const int* __restrict__ offs, const int* __restrict__ list,
    float* __restrict__ hbuf) {
  int bx = blockIdx.x;
  int e = bx >> 10;
  int rem = bx & 1023;
  int r = rem >> 5, c = rem & 31;
  int ne = cnt[e];
  if (r * 64 >= ne) return;
  int off = offs[e];

  __shared__ int stok[64];
  __shared__ __align__(16) float As[16 * 64];
  __shared__ __align__(16) float Bs[16 * 64];
  int tid = threadIdx.x;
  if (tid < 64) {
    int row = r * 64 + tid;
    stok[tid] = list[e * CAP + ((row < ne) ? row : (ne - 1))];
  }
  __syncthreads();

  int arow = tid & 63, kq = tid >> 6;
  const float* xrow = x + (size_t)stok[arow] * Dd + kq * 4;
  int bn = (tid & 15) * 4, bk = tid >> 4;
  const float* wrow = W1 + (size_t)e * Dd * Hh + (size_t)bk * Hh + c * 64 + bn;
  int tx = tid & 15, ty = tid >> 4;
  float acc[4][4] = {};

  for (int k0 = 0; k0 < Dd; k0 += 16) {
    float4 av = *(const float4*)(xrow + k0);
    float4 bv = *(const float4*)(wrow + (size_t)k0 * Hh);
    As[(kq * 4 + 0) * 64 + arow] = av.x;
    As[(kq * 4 + 1) * 64 + arow] = av.y;
    As[(kq * 4 + 2) * 64 + arow] = av.z;
    As[(kq * 4 + 3) * 64 + arow] = av.w;
    *(float4*)&Bs[bk * 64 + bn] = bv;
    __syncthreads();
#pragma unroll
    for (int k = 0; k < 16; k++) {
      float4 a = *(const float4*)&As[k * 64 + ty * 4];
      float4 b = *(const float4*)&Bs[k * 64 + tx * 4];
      acc[0][0] += a.x * b.x; acc[0][1] += a.x * b.y; acc[0][2] += a.x * b.z; acc[0][3] += a.x * b.w;
      acc[1][0] += a.y * b.x; acc[1][1] += a.y * b.y; acc[1][2] += a.y * b.z; acc[1][3] += a.y * b.w;
      acc[2][0] += a.z * b.x; acc[2][1] += a.z * b.y; acc[2][2] += a.z * b.z; acc[2][3] += a.z * b.w;
      acc[3][0] += a.w * b.x; acc[3][1] += a.w * b.y; acc[3][2] += a.w * b.z; acc[3][3] += a.w * b.w;
    }
    __syncthreads();
  }

  const float* b1e = b1 + (size_t)e * Hh + c * 64 + tx * 4;
#pragma unroll
  for (int i = 0; i < 4; i++) {
    int row = r * 64 + ty * 4 + i;
    if (row < ne) {
      float4 o;
      o.x = gelu_f(acc[i][0] + b1e[0]);
      o.y = gelu_f(acc[i][1] + b1e[1]);
      o.z = gelu_f(acc[i][2] + b1e[2]);
      o.w = gelu_f(acc[i][3] + b1e[3]);
      *(float4*)(hbuf + (size_t)(off + row) * Hh + c * 64 + tx * 4) = o;
    }
  }
}

// ------------------------------------------------------------------
// GEMM2: hbuf rows (ne x 2048) @ W2[e] (2048 x 512) + b2, scale by gate, atomic scatter to out
// grid: 8 * 32 * 8 = 2048 blocks x 256 thr
// ------------------------------------------------------------------
__global__ __launch_bounds__(256) void k_gemm2(
    const float* __restrict__ hbuf, const float* __restrict__ W2,
    const float* __restrict__ b2, const int* __restrict__ cnt,
    const int* __restrict__ offs, const int* __restrict__ list,
    const float* __restrict__ glist, float* __restrict__ out) {
  int bx = blockIdx.x;
  int e = bx >> 8;
  int rem = bx & 255;
  int r = rem >> 3, c = rem & 7;
  int ne = cnt[e];
  if (r * 64 >= ne) return;
  int off = offs[e];

  __shared__ __align__(16) float As[16 * 64];
  __shared__ __align__(16) float Bs[16 * 64];
  int tid = threadIdx.x;
  int arow = tid & 63, kq = tid >> 6;
  int lrow = r * 64 + arow;
  if (lrow >= ne) lrow = ne - 1;
  const float* hrow = hbuf + (size_t)(off + lrow) * Hh + kq * 4;
  int bn = (tid & 15) * 4, bk = tid >> 4;
  const float* wrow = W2 + (size_t)e * Hh * Dd + (size_t)bk * Dd + c * 64 + bn;
  int tx = tid & 15, ty = tid >> 4;
  float acc[4][4] = {};

  for (int k0 = 0; k0 < Hh; k0 += 16) {
    float4 av = *(const float4*)(hrow + k0);
    float4 bv = *(const float4*)(wrow + (size_t)k0 * Dd);
    As[(kq * 4 + 0) * 64 + arow] = av.x;
    As[(kq * 4 + 1) * 64 + arow] = av.y;
    As[(kq * 4 + 2) * 64 + arow] = av.z;
    As[(kq * 4 + 3) * 64 + arow] = av.w;
    *(float4*)&Bs[bk * 64 + bn] = bv;
    __syncthreads();
#pragma unroll
    for (int k = 0; k < 16; k++) {
      float4 a = *(const float4*)&As[k * 64 + ty * 4];
      float4 b = *(const float4*)&Bs[k * 64 + tx * 4];
      acc[0][0] += a.x * b.x; acc[0][1] += a.x * b.y; acc[0][2] += a.x * b.z; acc[0][3] += a.x * b.w;
      acc[1][0] += a.y * b.x; acc[1][1] += a.y * b.y; acc[1][2] += a.y * b.z; acc[1][3] += a.y * b.w;
      acc[2][0] += a.z * b.x; acc[2][1] += a.z * b.y; acc[2][2] += a.z * b.z; acc[2][3] += a.z * b.w;
      acc[3][0] += a.w * b.x; acc[3][1] += a.w * b.y; acc[3][2] += a.w * b.z; acc[3][3] += a.w * b.w;
    }
    __syncthreads();
  }

  const float* b2e = b2 + (size_t)e * Dd + c * 64 + tx * 4;
#pragma unroll
  for (int i = 0; i < 4; i++) {
    int row = r * 64 + ty * 4 + i;
    if (row < ne) {
      int tk = list[e * CAP + row];
      float g = glist[e * CAP + row];
      float* op = out + (size_t)tk * Dd + c * 64 + tx * 4;
      atomicAdd(&op[0], g * (acc[i][0] + b2e[0]));
      atomicAdd(&op[1], g * (acc[i][1] + b2e[1]));
      atomicAdd(&op[2], g * (acc[i][2] + b2e[2]));
      atomicAdd(&op[3], g * (acc[i][3] + b2e[3]));
    }
  }
}

__global__ void k_finalize(const float* __restrict__ imp,
                           const float* __restrict__ zsum,
                           const float* __restrict__ esum,
                           float* __restrict__ out) {
  if (threadIdx.x == 0 && blockIdx.x == 0) {
    float lb = 0.f;
#pragma unroll
    for (int e = 0; e < Ee; e++) {
      float v = imp[e] * (1.f / TOKENS) - (1.f / Ee);
      lb += v * v;
    }
    lb *= (1.f / Ee);
    float rz = zsum[0] * (1.f / TOKENS);
    float en = esum[0] * (1.f / TOKENS);
    float* s = out + (size_t)Bb * Ss * Dd;
    s[0] = lb;
    s[1] = rz;
    s[2] = en;
    s[3] = lb + 0.001f * rz - 0.001f * en;
  }
}

extern "C" void kernel_launch(void* const* d_in, const int* in_sizes, int n_in,
                              void* d_out, int out_size, void* d_ws, size_t ws_size,
                              hipStream_t stream) {
  const float* x = (const float*)d_in[0];
  const float* ctx = (const float*)d_in[1];
  const float* quality = (const float*)d_in[2];
  const float* rn_g = (const float*)d_in[3];
  const float* rn_b = (const float*)d_in[4];
  const float* cn_g = (const float*)d_in[5];
  const float* cn_b = (const float*)d_in[6];
  const float* ctx_W = (const float*)d_in[7];
  const float* ctx_b = (const float*)d_in[8];
  const float* qual_W = (const float*)d_in[9];
  const float* qual_b = (const float*)d_in[10];
  const float* rtr_W = (const float*)d_in[11];
  const float* rtr_b = (const float*)d_in[12];
  const float* temperature = (const float*)d_in[13];
  const float* W1 = (const float*)d_in[14];
  const float* b1 = (const float*)d_in[15];
  const float* W2 = (const float*)d_in[16];
  const float* b2 = (const float*)d_in[17];
  float* out = (float*)d_out;

  char* w = (char*)d_ws;
  int* cnt = (int*)(w + 0);
  int* offs = (int*)(w + 32);
  float* imp = (float*)(w + 64);
  float* zsum = (float*)(w + 96);
  float* esum = (float*)(w + 100);
  float* M1 = (float*)(w + 128);
  float* qv = (float*)(w + 16512);
  float* cb = (float*)(w + 16544);
  int* list = (int*)(w + 16640);
  float* glist = (float*)(w + 82176);
  float* hbuf = (float*)(w + 147712);

  hipMemsetAsync(d_out, 0, (size_t)out_size * sizeof(float), stream);
  hipMemsetAsync(d_ws, 0, 128, stream);

  k_precomp<<<513, 64, 0, stream>>>(ctx_W, rtr_W, rtr_b, qual_W, qual_b, ctx_b, M1, qv, cb);
  k_router<<<TOKENS, 256, 0, stream>>>(x, ctx, quality, rn_g, rn_b, cn_g, cn_b, rtr_W, M1,
                                       qv, cb, temperature, cnt, list, glist, imp, zsum, esum);
  k_offs<<<1, 64, 0, stream>>>(cnt, offs);
  k_gemm1<<<Ee * 32 * 32, 256, 0, stream>>>(x, W1, b1, cnt, offs, list, hbuf);
  k_gemm2<<<Ee * 32 * 8, 256, 0, stream>>>(hbuf, W2, b2, cnt, offs, list, glist, out);
  k_finalize<<<1, 64, 0, stream>>>(imp, zsum, esum, out);
}

// Round 2
// 621.933 us; speedup vs baseline: 1.4121x; 1.4121x over previous
//
#include <hip/hip_runtime.h>
#include <hip/hip_bf16.h>
#include <math.h>

#define Bb 4
#define Ss 512
#define Dd 512
#define Hh 2048
#define Ee 8
#define TOKENS 2048
#define CAP 2048

typedef __attribute__((ext_vector_type(8))) short bf16x8;
typedef __attribute__((ext_vector_type(4))) float f32x4;

// ---------------- ws layout (bytes) ----------------
#define WS_CNT   0
#define WS_OFFS  32
#define WS_IMP   64
#define WS_Z     96
#define WS_E     100
#define WS_M1    128
#define WS_QV    16512
#define WS_CB    16544
#define WS_LIST  16640
#define WS_GLIST 82176
#define WS_BASE  147712
// MFMA path buffers (bf16 hi/lo, ushort):
#define WS_XH  (WS_BASE)
#define WS_XL  (WS_XH + 2097152)
#define WS_W1H (WS_XL + 2097152)
#define WS_W1L (WS_W1H + 16777216)
#define WS_W2H (WS_W1L + 16777216)
#define WS_W2L (WS_W2H + 16777216)
#define WS_HH  (WS_W2L + 16777216)
#define WS_HL  (WS_HH + 16777216)
#define WS_NEED ((size_t)(WS_HL + 16777216))   // ~105 MB
// fp32 fallback path: hbuf (32 MB) at WS_BASE

__device__ __forceinline__ float wred(float v) {
#pragma unroll
  for (int o = 32; o > 0; o >>= 1) v += __shfl_down(v, o);
  return v;
}

__device__ __forceinline__ float block_sum(float v, float* s4, int tid) {
  v = wred(v);
  __syncthreads();
  if ((tid & 63) == 0) s4[tid >> 6] = v;
  __syncthreads();
  return s4[0] + s4[1] + s4[2] + s4[3];
}

__device__ __forceinline__ float gelu_f(float v) {
  return 0.5f * v * (1.0f + erff(v * 0.7071067811865475f));
}

__device__ __forceinline__ ushort2 splitbf(float v) {
  union { __hip_bfloat16 b; unsigned short u; } h, l;
  h.b = __float2bfloat16(v);
  l.b = __float2bfloat16(v - __bfloat162float(h.b));
  ushort2 r; r.x = h.u; r.y = l.u;
  return r;
}

#define GL16(gp, lp) __builtin_amdgcn_global_load_lds( \
    (const __attribute__((address_space(1))) void*)(gp), \
    (__attribute__((address_space(3))) void*)(lp), 16, 0, 0)

// ------------------------------------------------------------------
// Precompute M1 = ctx_W @ rtr_W, qv = qual_W@rtr_W, cb = (ctx_b+qual_b)@rtr_W + rtr_b
// ------------------------------------------------------------------
__global__ __launch_bounds__(64) void k_precomp(
    const float* __restrict__ ctx_W, const float* __restrict__ rtr_W,
    const float* __restrict__ rtr_b, const float* __restrict__ qual_W,
    const float* __restrict__ qual_b, const float* __restrict__ ctx_b,
    float* __restrict__ M1, float* __restrict__ qv, float* __restrict__ cb) {
  int d = blockIdx.x;
  int lane = threadIdx.x;
  if (d < Dd) {
    float acc[Ee] = {0.f, 0.f, 0.f, 0.f, 0.f, 0.f, 0.f, 0.f};
    for (int k = lane; k < Dd; k += 64) {
      float cw = ctx_W[d * Dd + k];
      const float* r = rtr_W + k * Ee;
#pragma unroll
      for (int e = 0; e < Ee; e++) acc[e] += cw * r[e];
    }
#pragma unroll
    for (int e = 0; e < Ee; e++) acc[e] = wred(acc[e]);
    if (lane == 0) {
#pragma unroll
      for (int e = 0; e < Ee; e++) M1[d * Ee + e] = acc[e];
    }
  } else {
    float aq[Ee] = {0.f, 0.f, 0.f, 0.f, 0.f, 0.f, 0.f, 0.f};
    float ab[Ee] = {0.f, 0.f, 0.f, 0.f, 0.f, 0.f, 0.f, 0.f};
    for (int k = lane; k < Dd; k += 64) {
      float qw = qual_W[k];
      float bb = ctx_b[k] + qual_b[k];
      const float* r = rtr_W + k * Ee;
#pragma unroll
      for (int e = 0; e < Ee; e++) {
        aq[e] += qw * r[e];
        ab[e] += bb * r[e];
      }
    }
#pragma unroll
    for (int e = 0; e < Ee; e++) {
      aq[e] = wred(aq[e]);
      ab[e] = wred(ab[e]);
    }
    if (lane == 0) {
#pragma unroll
      for (int e = 0; e < Ee; e++) {
        qv[e] = aq[e];
        cb[e] = ab[e] + rtr_b[e];
      }
    }
  }
}

// ------------------------------------------------------------------
// Router (unchanged from passing version)
// ------------------------------------------------------------------
__global__ __launch_bounds__(256) void k_router(
    const float* __restrict__ x, const float* __restrict__ ctx,
    const float* __restrict__ quality, const float* __restrict__ rn_g,
    const float* __restrict__ rn_b, const float* __restrict__ cn_g,
    const float* __restrict__ cn_b, const float* __restrict__ rtr_W,
    const float* __restrict__ M1, const float* __restrict__ qv,
    const float* __restrict__ cb, const float* __restrict__ temperature,
    int* __restrict__ cnt, int* __restrict__ list, float* __restrict__ glist,
    float* __restrict__ imp, float* __restrict__ zsum, float* __restrict__ esum) {
  int t = blockIdx.x;
  int tid = threadIdx.x;
  __shared__ float s4[4];
  __shared__ float slg[4][Ee];

  const float* xr = x + (size_t)t * Dd;
  const float* cr = ctx + (size_t)t * Dd;
  float x0 = xr[tid], x1 = xr[tid + 256];
  float c0 = cr[tid], c1 = cr[tid + 256];

  float sx = block_sum(x0 + x1, s4, tid);
  float sc = block_sum(c0 + c1, s4, tid);
  float mx = sx * (1.f / Dd), mc = sc * (1.f / Dd);
  float vx = block_sum((x0 - mx) * (x0 - mx) + (x1 - mx) * (x1 - mx), s4, tid);
  float vc = block_sum((c0 - mc) * (c0 - mc) + (c1 - mc) * (c1 - mc), s4, tid);
  float rsx = rsqrtf(vx * (1.f / Dd) + 1e-5f);
  float rsc = rsqrtf(vc * (1.f / Dd) + 1e-5f);

  float lg[Ee] = {0.f, 0.f, 0.f, 0.f, 0.f, 0.f, 0.f, 0.f};
  {
    int d = tid;
    float xn = (x0 - mx) * rsx * rn_g[d] + rn_b[d];
    float cn = (c0 - mc) * rsc * cn_g[d] + cn_b[d];
    const float* rw = rtr_W + d * Ee;
    const float* m1 = M1 + d * Ee;
#pragma unroll
    for (int e = 0; e < Ee; e++) lg[e] += xn * rw[e] + cn * m1[e];
    d = tid + 256;
    xn = (x1 - mx) * rsx * rn_g[d] + rn_b[d];
    cn = (c1 - mc) * rsc * cn_g[d] + cn_b[d];
    rw = rtr_W + d * Ee;
    m1 = M1 + d * Ee;
#pragma unroll
    for (int e = 0; e < Ee; e++) lg[e] += xn * rw[e] + cn * m1[e];
  }
#pragma unroll
  for (int e = 0; e < Ee; e++) lg[e] = wred(lg[e]);
  if ((tid & 63) == 0) {
#pragma unroll
    for (int e = 0; e < Ee; e++) slg[tid >> 6][e] = lg[e];
  }
  __syncthreads();

  if (tid == 0) {
    float invT = 1.f / fmaxf(temperature[0], 0.25f);
    int b = t / Ss;
    float q = quality[b];
    float L[Ee];
#pragma unroll
    for (int e = 0; e < Ee; e++)
      L[e] = (slg[0][e] + slg[1][e] + slg[2][e] + slg[3][e] + q * qv[e] + cb[e]) * invT;

    int i0 = 0;
#pragma unroll
    for (int e = 1; e < Ee; e++)
      if (L[e] > L[i0]) i0 = e;
    int i1 = (i0 == 0) ? 1 : 0;
#pragma unroll
    for (int e = 0; e < Ee; e++)
      if (e != i0 && L[e] > L[i1]) i1 = e;

    float e1 = __expf(L[i1] - L[i0]);
    float g0 = 1.f / (1.f + e1);
    float g1 = e1 / (1.f + e1);

    float m = L[i0];
    float p[Ee];
    float sum = 0.f;
#pragma unroll
    for (int e = 0; e < Ee; e++) {
      p[e] = __expf(L[e] - m);
      sum += p[e];
    }
    float lse = m + __logf(sum);
    float inv = 1.f / sum;
    float ent = 0.f;
#pragma unroll
    for (int e = 0; e < Ee; e++) {
      p[e] *= inv;
      ent -= p[e] * __logf(fmaxf(p[e], 1e-9f));
      atomicAdd(&imp[e], p[e]);
    }
    atomicAdd(zsum, lse * lse);
    atomicAdd(esum, ent);

    int p0 = atomicAdd(&cnt[i0], 1);
    list[i0 * CAP + p0] = t;
    glist[i0 * CAP + p0] = g0;
    int p1 = atomicAdd(&cnt[i1], 1);
    list[i1 * CAP + p1] = t;
    glist[i1 * CAP + p1] = g1;
  }
}

__global__ void k_offs(const int* __restrict__ cnt, int* __restrict__ offs) {
  if (threadIdx.x == 0 && blockIdx.x == 0) {
    int s = 0;
#pragma unroll
    for (int e = 0; e < Ee; e++) {
      offs[e] = s;
      s += cnt[e];
    }
  }
}

// ------------------------------------------------------------------
// Conversions for MFMA path
// ------------------------------------------------------------------
__global__ __launch_bounds__(256) void k_convx(const float* __restrict__ x,
    ushort* __restrict__ xh, ushort* __restrict__ xl) {
  int i = (blockIdx.x * 256 + threadIdx.x) * 4;
  float4 v = *(const float4*)(x + i);
  ushort4 h, l;
  ushort2 s;
  s = splitbf(v.x); h.x = s.x; l.x = s.y;
  s = splitbf(v.y); h.y = s.x; l.y = s.y;
  s = splitbf(v.z); h.z = s.x; l.z = s.y;
  s = splitbf(v.w); h.w = s.x; l.w = s.y;
  *(ushort4*)(xh + i) = h;
  *(ushort4*)(xl + i) = l;
}

// transpose per expert [R][C] -> [C][R], split into bf16 hi/lo
__global__ __launch_bounds__(256) void k_convT(const float* __restrict__ src,
    ushort* __restrict__ dh, ushort* __restrict__ dl, int R, int C) {
  int nr = R >> 6, ncc = C >> 6;
  int bx = blockIdx.x;
  int e = bx / (nr * ncc);
  int rem = bx % (nr * ncc);
  int rt = rem / ncc, ct = rem % ncc;
  __shared__ float ls[64 * 65];
  int tid = threadIdx.x;
  const float* s0 = src + (size_t)e * R * C + (size_t)(rt * 64) * C + ct * 64;
#pragma unroll
  for (int j = 0; j < 4; j++) {
    int li = j * 256 + tid;
    int rr = li >> 4, c4 = (li & 15) << 2;
    float4 v = *(const float4*)(s0 + (size_t)rr * C + c4);
    ls[rr * 65 + c4] = v.x;
    ls[rr * 65 + c4 + 1] = v.y;
    ls[rr * 65 + c4 + 2] = v.z;
    ls[rr * 65 + c4 + 3] = v.w;
  }
  __syncthreads();
#pragma unroll
  for (int j = 0; j < 4; j++) {
    int li = j * 256 + tid;
    int on = li >> 4, k4 = (li & 15) << 2;
    ushort4 h, l;
    ushort2 s;
    s = splitbf(ls[(k4 + 0) * 65 + on]); h.x = s.x; l.x = s.y;
    s = splitbf(ls[(k4 + 1) * 65 + on]); h.y = s.x; l.y = s.y;
    s = splitbf(ls[(k4 + 2) * 65 + on]); h.z = s.x; l.z = s.y;
    s = splitbf(ls[(k4 + 3) * 65 + on]); h.w = s.x; l.w = s.y;
    size_t p = ((size_t)e * C + ct * 64 + on) * R + rt * 64 + k4;
    *(ushort4*)(dh + p) = h;
    *(ushort4*)(dl + p) = l;
  }
}

// ------------------------------------------------------------------
// MFMA GEMM1: gathered X rows (ne x 512) @ W1[e] (512 x 2048), gelu, split-> hh/hl
// 128x128 tile, BK=32, 4 waves, bf16x3. grid: 8e x 16r x 16c
// ------------------------------------------------------------------
__global__ __launch_bounds__(256) void k_mg1(
    const ushort* __restrict__ xh, const ushort* __restrict__ xl,
    const ushort* __restrict__ w1h, const ushort* __restrict__ w1l,
    const float* __restrict__ b1,
    const int* __restrict__ cnt, const int* __restrict__ offs,
    const int* __restrict__ list,
    ushort* __restrict__ hh, ushort* __restrict__ hl) {
  int bx = blockIdx.x;
  int e = bx >> 8;
  int r = (bx >> 4) & 15;
  int c = bx & 15;
  int ne = cnt[e];
  if (r * 128 >= ne) return;
  int off = offs[e];

  __shared__ ushort As[2][4096];  // [hi/lo][g:4][row:128][8]
  __shared__ ushort Bs[2][4096];
  __shared__ int stok[128];

  int tid = threadIdx.x;
  if (tid < 128) {
    int row = r * 128 + tid;
    stok[tid] = list[e * CAP + ((row < ne) ? row : (ne - 1))];
  }
  __syncthreads();

  int idx0 = tid, idx1 = 256 + tid;
  int g0 = idx0 >> 7, row0 = idx0 & 127;
  int g1 = idx1 >> 7, row1 = idx1 & 127;
  size_t aoff0 = (size_t)stok[row0] * Dd + g0 * 8;
  size_t aoff1 = (size_t)stok[row1] * Dd + g1 * 8;
  size_t boff0 = ((size_t)(e * Hh + c * 128 + row0)) * Dd + g0 * 8;
  size_t boff1 = ((size_t)(e * Hh + c * 128 + row1)) * Dd + g1 * 8;
  ushort* lA0 = &As[0][idx0 * 8]; ushort* lA1 = &As[0][idx1 * 8];
  ushort* lA0l = &As[1][idx0 * 8]; ushort* lA1l = &As[1][idx1 * 8];
  ushort* lB0 = &Bs[0][idx0 * 8]; ushort* lB1 = &Bs[0][idx1 * 8];
  ushort* lB0l = &Bs[1][idx0 * 8]; ushort* lB1l = &Bs[1][idx1 * 8];

  int lane = tid & 63, wid = tid >> 6;
  int wm = wid >> 1, wn = wid & 1;
  int l15 = lane & 15, lg = lane >> 4;

  f32x4 acc[4][4] = {};

  for (int k0 = 0; k0 < Dd; k0 += 32) {
    GL16(xh + aoff0 + k0, lA0);
    GL16(xh + aoff1 + k0, lA1);
    GL16(xl + aoff0 + k0, lA0l);
    GL16(xl + aoff1 + k0, lA1l);
    GL16(w1h + boff0 + k0, lB0);
    GL16(w1h + boff1 + k0, lB1);
    GL16(w1l + boff0 + k0, lB0l);
    GL16(w1l + boff1 + k0, lB1l);
    __syncthreads();

    bf16x8 ah[4], al[4], bh[4], bl[4];
#pragma unroll
    for (int m = 0; m < 4; m++) {
      int o = (lg * 128 + wm * 64 + m * 16 + l15) * 8;
      ah[m] = *(const bf16x8*)&As[0][o];
      al[m] = *(const bf16x8*)&As[1][o];
    }
#pragma unroll
    for (int n = 0; n < 4; n++) {
      int o = (lg * 128 + wn * 64 + n * 16 + l15) * 8;
      bh[n] = *(const bf16x8*)&Bs[0][o];
      bl[n] = *(const bf16x8*)&Bs[1][o];
    }
#pragma unroll
    for (int m = 0; m < 4; m++)
#pragma unroll
      for (int n = 0; n < 4; n++) {
        acc[m][n] = __builtin_amdgcn_mfma_f32_16x16x32_bf16(ah[m], bh[n], acc[m][n], 0, 0, 0);
        acc[m][n] = __builtin_amdgcn_mfma_f32_16x16x32_bf16(ah[m], bl[n], acc[m][n], 0, 0, 0);
        acc[m][n] = __builtin_amdgcn_mfma_f32_16x16x32_bf16(al[m], bh[n], acc[m][n], 0, 0, 0);
      }
    __syncthreads();
  }

  int lg4 = lg * 4;
#pragma unroll
  for (int n = 0; n < 4; n++) {
    int colg = c * 128 + wn * 64 + n * 16 + l15;
    float bias = b1[e * Hh + colg];
#pragma unroll
    for (int m = 0; m < 4; m++) {
#pragma unroll
      for (int j = 0; j < 4; j++) {
        int rowl = r * 128 + wm * 64 + m * 16 + lg4 + j;
        if (rowl < ne) {
          float v = gelu_f(acc[m][n][j] + bias);
          ushort2 s = splitbf(v);
          size_t p = (size_t)(off + rowl) * Hh + colg;
          hh[p] = s.x;
          hl[p] = s.y;
        }
      }
    }
  }
}

// ------------------------------------------------------------------
// MFMA GEMM2: hh/hl rows (ne x 2048) @ W2[e] (2048 x 512), +b2, gate, atomic scatter
// 128x128 tile, BK=32, split-K=2. grid: 8e x 16r x 4c x 2k
// ------------------------------------------------------------------
__global__ __launch_bounds__(256) void k_mg2(
    const ushort* __restrict__ hh, const ushort* __restrict__ hl,
    const ushort* __restrict__ w2h, const ushort* __restrict__ w2l,
    const float* __restrict__ b2,
    const int* __restrict__ cnt, const int* __restrict__ offs,
    const int* __restrict__ list, const float* __restrict__ glist,
    float* __restrict__ out) {
  int bx = blockIdx.x;
  int e = bx >> 7;
  int r = (bx >> 3) & 15;
  int c = (bx >> 1) & 3;
  int kS = bx & 1;
  int ne = cnt[e];
  if (r * 128 >= ne) return;
  int off = offs[e];

  __shared__ ushort As[2][4096];
  __shared__ ushort Bs[2][4096];

  int tid = threadIdx.x;
  int idx0 = tid, idx1 = 256 + tid;
  int g0 = idx0 >> 7, row0 = idx0 & 127;
  int g1 = idx1 >> 7, row1 = idx1 & 127;
  int ar0 = r * 128 + row0; if (ar0 >= ne) ar0 = ne - 1;
  int ar1 = r * 128 + row1; if (ar1 >= ne) ar1 = ne - 1;
  size_t kbase = (size_t)kS * 1024;
  size_t aoff0 = (size_t)(off + ar0) * Hh + kbase + g0 * 8;
  size_t aoff1 = (size_t)(off + ar1) * Hh + kbase + g1 * 8;
  size_t boff0 = ((size_t)(e * Dd + c * 128 + row0)) * Hh + kbase + g0 * 8;
  size_t boff1 = ((size_t)(e * Dd + c * 128 + row1)) * Hh + kbase + g1 * 8;
  ushort* lA0 = &As[0][idx0 * 8]; ushort* lA1 = &As[0][idx1 * 8];
  ushort* lA0l = &As[1][idx0 * 8]; ushort* lA1l = &As[1][idx1 * 8];
  ushort* lB0 = &Bs[0][idx0 * 8]; ushort* lB1 = &Bs[0][idx1 * 8];
  ushort* lB0l = &Bs[1][idx0 * 8]; ushort* lB1l = &Bs[1][idx1 * 8];

  int lane = tid & 63, wid = tid >> 6;
  int wm = wid >> 1, wn = wid & 1;
  int l15 = lane & 15, lg = lane >> 4;

  f32x4 acc[4][4] = {};

  for (int k0 = 0; k0 < 1024; k0 += 32) {
    GL16(hh + aoff0 + k0, lA0);
    GL16(hh + aoff1 + k0, lA1);
    GL16(hl + aoff0 + k0, lA0l);
    GL16(hl + aoff1 + k0, lA1l);
    GL16(w2h + boff0 + k0, lB0);
    GL16(w2h + boff1 + k0, lB1);
    GL16(w2l + boff0 + k0, lB0l);
    GL16(w2l + boff1 + k0, lB1l);
    __syncthreads();

    bf16x8 ah[4], al[4], bh[4], bl[4];
#pragma unroll
    for (int m = 0; m < 4; m++) {
      int o = (lg * 128 + wm * 64 + m * 16 + l15) * 8;
      ah[m] = *(const bf16x8*)&As[0][o];
      al[m] = *(const bf16x8*)&As[1][o];
    }
#pragma unroll
    for (int n = 0; n < 4; n++) {
      int o = (lg * 128 + wn * 64 + n * 16 + l15) * 8;
      bh[n] = *(const bf16x8*)&Bs[0][o];
      bl[n] = *(const bf16x8*)&Bs[1][o];
    }
#pragma unroll
    for (int m = 0; m < 4; m++)
#pragma unroll
      for (int n = 0; n < 4; n++) {
        acc[m][n] = __builtin_amdgcn_mfma_f32_16x16x32_bf16(ah[m], bh[n], acc[m][n], 0, 0, 0);
        acc[m][n] = __builtin_amdgcn_mfma_f32_16x16x32_bf16(ah[m], bl[n], acc[m][n], 0, 0, 0);
        acc[m][n] = __builtin_amdgcn_mfma_f32_16x16x32_bf16(al[m], bh[n], acc[m][n], 0, 0, 0);
      }
    __syncthreads();
  }

  int lg4 = lg * 4;
#pragma unroll
  for (int m = 0; m < 4; m++) {
#pragma unroll
    for (int j = 0; j < 4; j++) {
      int rowl = r * 128 + wm * 64 + m * 16 + lg4 + j;
      if (rowl < ne) {
        int tok = list[e * CAP + rowl];
        float gte = glist[e * CAP + rowl];
#pragma unroll
        for (int n = 0; n < 4; n++) {
          int colg = c * 128 + wn * 64 + n * 16 + l15;
          float v = acc[m][n][j] + (kS == 0 ? b2[e * Dd + colg] : 0.f);
          atomicAdd(&out[(size_t)tok * Dd + colg], gte * v);
        }
      }
    }
  }
}

// ------------------------------------------------------------------
// fp32 fallback GEMMs (used only if ws_size < WS_NEED)
// ------------------------------------------------------------------
__global__ __launch_bounds__(256) void k_gemm1_f32(
    const float* __restrict__ x, const float* __restrict__ W1,
    const float* __restrict__ b1, const int* __restrict__ cnt,
    const int* __restrict__ offs, const int* __restrict__ list,
    float* __restrict__ hbuf) {
  int bx = blockIdx.x;
  int e = bx >> 10;
  int rem = bx & 1023;
  int r = rem >> 5, c = rem & 31;
  int ne = cnt[e];
  if (r * 64 >= ne) return;
  int off = offs[e];

  __shared__ int stok[64];
  __shared__ __align__(16) float As[16 * 64];
  __shared__ __align__(16) float Bs[16 * 64];
  int tid = threadIdx.x;
  if (tid < 64) {
    int row = r * 64 + tid;
    stok[tid] = list[e * CAP + ((row < ne) ? row : (ne - 1))];
  }
  __syncthreads();

  int arow = tid & 63, kq = tid >> 6;
  const float* xrow = x + (size_t)stok[arow] * Dd + kq * 4;
  int bn = (tid & 15) * 4, bk = tid >> 4;
  const float* wrow = W1 + (size_t)e * Dd * Hh + (size_t)bk * Hh + c * 64 + bn;
  int tx = tid & 15, ty = tid >> 4;
  float acc[4][4] = {};

  for (int k0 = 0; k0 < Dd; k0 += 16) {
    float4 av = *(const float4*)(xrow + k0);
    float4 bv = *(const float4*)(wrow + (size_t)k0 * Hh);
    As[(kq * 4 + 0) * 64 + arow] = av.x;
    As[(kq * 4 + 1) * 64 + arow] = av.y;
    As[(kq * 4 + 2) * 64 + arow] = av.z;
    As[(kq * 4 + 3) * 64 + arow] = av.w;
    *(float4*)&Bs[bk * 64 + bn] = bv;
    __syncthreads();
#pragma unroll
    for (int k = 0; k < 16; k++) {
      float4 a = *(const float4*)&As[k * 64 + ty * 4];
      float4 b = *(const float4*)&Bs[k * 64 + tx * 4];
      acc[0][0] += a.x * b.x; acc[0][1] += a.x * b.y; acc[0][2] += a.x * b.z; acc[0][3] += a.x * b.w;
      acc[1][0] += a.y * b.x; acc[1][1] += a.y * b.y; acc[1][2] += a.y * b.z; acc[1][3] += a.y * b.w;
      acc[2][0] += a.z * b.x; acc[2][1] += a.z * b.y; acc[2][2] += a.z * b.z; acc[2][3] += a.z * b.w;
      acc[3][0] += a.w * b.x; acc[3][1] += a.w * b.y; acc[3][2] += a.w * b.z; acc[3][3] += a.w * b.w;
    }
    __syncthreads();
  }

  const float* b1e = b1 + (size_t)e * Hh + c * 64 + tx * 4;
#pragma unroll
  for (int i = 0; i < 4; i++) {
    int row = r * 64 + ty * 4 + i;
    if (row < ne) {
      float4 o;
      o.x = gelu_f(acc[i][0] + b1e[0]);
      o.y = gelu_f(acc[i][1] + b1e[1]);
      o.z = gelu_f(acc[i][2] + b1e[2]);
      o.w = gelu_f(acc[i][3] + b1e[3]);
      *(float4*)(hbuf + (size_t)(off + row) * Hh + c * 64 + tx * 4) = o;
    }
  }
}

__global__ __launch_bounds__(256) void k_gemm2_f32(
    const float* __restrict__ hbuf, const float* __restrict__ W2,
    const float* __restrict__ b2, const int* __restrict__ cnt,
    const int* __restrict__ offs, const int* __restrict__ list,
    const float* __restrict__ glist, float* __restrict__ out) {
  int bx = blockIdx.x;
  int e = bx >> 8;
  int rem = bx & 255;
  int r = rem >> 3, c = rem & 7;
  int ne = cnt[e];
  if (r * 64 >= ne) return;
  int off = offs[e];

  __shared__ __align__(16) float As[16 * 64];
  __shared__ __align__(16) float Bs[16 * 64];
  int tid = threadIdx.x;
  int arow = tid & 63, kq = tid >> 6;
  int lrow = r * 64 + arow;
  if (lrow >= ne) lrow = ne - 1;
  const float* hrow = hbuf + (size_t)(off + lrow) * Hh + kq * 4;
  int bn = (tid & 15) * 4, bk = tid >> 4;
  const float* wrow = W2 + (size_t)e * Hh * Dd + (size_t)bk * Dd + c * 64 + bn;
  int tx = tid & 15, ty = tid >> 4;
  float acc[4][4] = {};

  for (int k0 = 0; k0 < Hh; k0 += 16) {
    float4 av = *(const float4*)(hrow + k0);
    float4 bv = *(const float4*)(wrow + (size_t)k0 * Dd);
    As[(kq * 4 + 0) * 64 + arow] = av.x;
    As[(kq * 4 + 1) * 64 + arow] = av.y;
    As[(kq * 4 + 2) * 64 + arow] = av.z;
    As[(kq * 4 + 3) * 64 + arow] = av.w;
    *(float4*)&Bs[bk * 64 + bn] = bv;
    __syncthreads();
#pragma unroll
    for (int k = 0; k < 16; k++) {
      float4 a = *(const float4*)&As[k * 64 + ty * 4];
      float4 b = *(const float4*)&Bs[k * 64 + tx * 4];
      acc[0][0] += a.x * b.x; acc[0][1] += a.x * b.y; acc[0][2] += a.x * b.z; acc[0][3] += a.x * b.w;
      acc[1][0] += a.y * b.x; acc[1][1] += a.y * b.y; acc[1][2] += a.y * b.z; acc[1][3] += a.y * b.w;
      acc[2][0] += a.z * b.x; acc[2][1] += a.z * b.y; acc[2][2] += a.z * b.z; acc[2][3] += a.z * b.w;
      acc[3][0] += a.w * b.x; acc[3][1] += a.w * b.y; acc[3][2] += a.w * b.z; acc[3][3] += a.w * b.w;
    }
    __syncthreads();
  }

  const float* b2e = b2 + (size_t)e * Dd + c * 64 + tx * 4;
#pragma unroll
  for (int i = 0; i < 4; i++) {
    int row = r * 64 + ty * 4 + i;
    if (row < ne) {
      int tk = list[e * CAP + row];
      float g = glist[e * CAP + row];
      float* op = out + (size_t)tk * Dd + c * 64 + tx * 4;
      atomicAdd(&op[0], g * (acc[i][0] + b2e[0]));
      atomicAdd(&op[1], g * (acc[i][1] + b2e[1]));
      atomicAdd(&op[2], g * (acc[i][2] + b2e[2]));
      atomicAdd(&op[3], g * (acc[i][3] + b2e[3]));
    }
  }
}

__global__ void k_finalize(const float* __restrict__ imp,
                           const float* __restrict__ zsum,
                           const float* __restrict__ esum,
                           float* __restrict__ out) {
  if (threadIdx.x == 0 && blockIdx.x == 0) {
    float lb = 0.f;
#pragma unroll
    for (int e = 0; e < Ee; e++) {
      float v = imp[e] * (1.f / TOKENS) - (1.f / Ee);
      lb += v * v;
    }
    lb *= (1.f / Ee);
    float rz = zsum[0] * (1.f / TOKENS);
    float en = esum[0] * (1.f / TOKENS);
    float* s = out + (size_t)Bb * Ss * Dd;
    s[0] = lb;
    s[1] = rz;
    s[2] = en;
    s[3] = lb + 0.001f * rz - 0.001f * en;
  }
}

extern "C" void kernel_launch(void* const* d_in, const int* in_sizes, int n_in,
                              void* d_out, int out_size, void* d_ws, size_t ws_size,
                              hipStream_t stream) {
  const float* x = (const float*)d_in[0];
  const float* ctx = (const float*)d_in[1];
  const float* quality = (const float*)d_in[2];
  const float* rn_g = (const float*)d_in[3];
  const float* rn_b = (const float*)d_in[4];
  const float* cn_g = (const float*)d_in[5];
  const float* cn_b = (const float*)d_in[6];
  const float* ctx_W = (const float*)d_in[7];
  const float* ctx_b = (const float*)d_in[8];
  const float* qual_W = (const float*)d_in[9];
  const float* qual_b = (const float*)d_in[10];
  const float* rtr_W = (const float*)d_in[11];
  const float* rtr_b = (const float*)d_in[12];
  const float* temperature = (const float*)d_in[13];
  const float* W1 = (const float*)d_in[14];
  const float* b1 = (const float*)d_in[15];
  const float* W2 = (const float*)d_in[16];
  const float* b2 = (const float*)d_in[17];
  float* out = (float*)d_out;

  char* w = (char*)d_ws;
  int* cnt = (int*)(w + WS_CNT);
  int* offs = (int*)(w + WS_OFFS);
  float* imp = (float*)(w + WS_IMP);
  float* zsum = (float*)(w + WS_Z);
  float* esum = (float*)(w + WS_E);
  float* M1 = (float*)(w + WS_M1);
  float* qv = (float*)(w + WS_QV);
  float* cb = (float*)(w + WS_CB);
  int* list = (int*)(w + WS_LIST);
  float* glist = (float*)(w + WS_GLIST);

  hipMemsetAsync(d_out, 0, (size_t)out_size * sizeof(float), stream);
  hipMemsetAsync(d_ws, 0, 128, stream);

  k_precomp<<<513, 64, 0, stream>>>(ctx_W, rtr_W, rtr_b, qual_W, qual_b, ctx_b, M1, qv, cb);
  k_router<<<TOKENS, 256, 0, stream>>>(x, ctx, quality, rn_g, rn_b, cn_g, cn_b, rtr_W, M1,
                                       qv, cb, temperature, cnt, list, glist, imp, zsum, esum);
  k_offs<<<1, 64, 0, stream>>>(cnt, offs);

  if (ws_size >= WS_NEED) {
    ushort* xh = (ushort*)(w + WS_XH);
    ushort* xl = (ushort*)(w + WS_XL);
    ushort* w1h = (ushort*)(w + WS_W1H);
    ushort* w1l = (ushort*)(w + WS_W1L);
    ushort* w2h = (ushort*)(w + WS_W2H);
    ushort* w2l = (ushort*)(w + WS_W2L);
    ushort* hh = (ushort*)(w + WS_HH);
    ushort* hl = (ushort*)(w + WS_HL);
    k_convx<<<1024, 256, 0, stream>>>(x, xh, xl);
    k_convT<<<Ee * 8 * 32, 256, 0, stream>>>(W1, w1h, w1l, Dd, Hh);
    k_convT<<<Ee * 32 * 8, 256, 0, stream>>>(W2, w2h, w2l, Hh, Dd);
    k_mg1<<<Ee * 16 * 16, 256, 0, stream>>>(xh, xl, w1h, w1l, b1, cnt, offs, list, hh, hl);
    k_mg2<<<Ee * 16 * 4 * 2, 256, 0, stream>>>(hh, hl, w2h, w2l, b2, cnt, offs, list, glist, out);
  } else {
    float* hbuf = (float*)(w + WS_BASE);
    k_gemm1_f32<<<Ee * 32 * 32, 256, 0, stream>>>(x, W1, b1, cnt, offs, list, hbuf);
    k_gemm2_f32<<<Ee * 32 * 8, 256, 0, stream>>>(hbuf, W2, b2, cnt, offs, list, glist, out);
  }
  k_finalize<<<1, 64, 0, stream>>>(imp, zsum, esum, out);
}

// Round 3
// 374.416 us; speedup vs baseline: 2.3456x; 1.6611x over previous
//
#include <hip/hip_runtime.h>
#include <hip/hip_bf16.h>
#include <math.h>

#define Bb 4
#define Ss 512
#define Dd 512
#define Hh 2048
#define Ee 8
#define TOKENS 2048
#define CAP 2048

typedef __attribute__((ext_vector_type(8))) short bf16x8;
typedef __attribute__((ext_vector_type(4))) float f32x4;

// ---------------- ws layout (bytes) ----------------
#define WS_CNT   0
#define WS_OFFS  32
#define WS_M1    128
#define WS_QV    16512
#define WS_CB    16544
#define WS_LIST  16640
#define WS_GLIST 82176
#define WS_LOG   147712            // float logits[2048][8] = 64 KiB
#define WS_XH    (WS_LOG + 65536)
#define WS_XL    (WS_XH + 2097152)
#define WS_W1H   (WS_XL + 2097152)
#define WS_W1L   (WS_W1H + 16777216)
#define WS_W2H   (WS_W1L + 16777216)
#define WS_W2L   (WS_W2H + 16777216)
#define WS_HH    (WS_W2L + 16777216)
#define WS_HL    (WS_HH + 16777216)

__device__ __forceinline__ float wred(float v) {
#pragma unroll
  for (int o = 32; o > 0; o >>= 1) v += __shfl_down(v, o);
  return v;
}

__device__ __forceinline__ float wredx(float v) {
#pragma unroll
  for (int o = 32; o > 0; o >>= 1) v += __shfl_xor(v, o);
  return v;
}

__device__ __forceinline__ float block_sum(float v, float* s4, int tid) {
  v = wred(v);
  __syncthreads();
  if ((tid & 63) == 0) s4[tid >> 6] = v;
  __syncthreads();
  return s4[0] + s4[1] + s4[2] + s4[3];
}

__device__ __forceinline__ float gelu_f(float v) {
  return 0.5f * v * (1.0f + erff(v * 0.7071067811865475f));
}

__device__ __forceinline__ ushort2 splitbf(float v) {
  union { __hip_bfloat16 b; unsigned short u; } h, l;
  h.b = __float2bfloat16(v);
  l.b = __float2bfloat16(v - __bfloat162float(h.b));
  ushort2 r; r.x = h.u; r.y = l.u;
  return r;
}

#define GL16(gp, lp) __builtin_amdgcn_global_load_lds( \
    (const __attribute__((address_space(1))) void*)(gp), \
    (__attribute__((address_space(3))) void*)(lp), 16, 0, 0)

// ------------------------------------------------------------------
// Precompute M1 = ctx_W @ rtr_W, qv = qual_W@rtr_W, cb = (ctx_b+qual_b)@rtr_W + rtr_b
// ------------------------------------------------------------------
__global__ __launch_bounds__(64) void k_precomp(
    const float* __restrict__ ctx_W, const float* __restrict__ rtr_W,
    const float* __restrict__ rtr_b, const float* __restrict__ qual_W,
    const float* __restrict__ qual_b, const float* __restrict__ ctx_b,
    float* __restrict__ M1, float* __restrict__ qv, float* __restrict__ cb) {
  int d = blockIdx.x;
  int lane = threadIdx.x;
  if (d < Dd) {
    float acc[Ee] = {0.f, 0.f, 0.f, 0.f, 0.f, 0.f, 0.f, 0.f};
    for (int k = lane; k < Dd; k += 64) {
      float cw = ctx_W[d * Dd + k];
      const float* r = rtr_W + k * Ee;
#pragma unroll
      for (int e = 0; e < Ee; e++) acc[e] += cw * r[e];
    }
#pragma unroll
    for (int e = 0; e < Ee; e++) acc[e] = wred(acc[e]);
    if (lane == 0) {
#pragma unroll
      for (int e = 0; e < Ee; e++) M1[d * Ee + e] = acc[e];
    }
  } else {
    float aq[Ee] = {0.f, 0.f, 0.f, 0.f, 0.f, 0.f, 0.f, 0.f};
    float ab[Ee] = {0.f, 0.f, 0.f, 0.f, 0.f, 0.f, 0.f, 0.f};
    for (int k = lane; k < Dd; k += 64) {
      float qw = qual_W[k];
      float bb = ctx_b[k] + qual_b[k];
      const float* r = rtr_W + k * Ee;
#pragma unroll
      for (int e = 0; e < Ee; e++) {
        aq[e] += qw * r[e];
        ab[e] += bb * r[e];
      }
    }
#pragma unroll
    for (int e = 0; e < Ee; e++) {
      aq[e] = wred(aq[e]);
      ab[e] = wred(ab[e]);
    }
    if (lane == 0) {
#pragma unroll
      for (int e = 0; e < Ee; e++) {
        qv[e] = aq[e];
        cb[e] = ab[e] + rtr_b[e];
      }
    }
  }
}

// ------------------------------------------------------------------
// Logits: one wave per token. LN(x), LN(ctx), 8 logits, write to ws.
// grid: 512 blocks x 256 thr (4 waves)
// ------------------------------------------------------------------
__global__ __launch_bounds__(256) void k_logits(
    const float* __restrict__ x, const float* __restrict__ ctx,
    const float* __restrict__ quality, const float* __restrict__ rn_g,
    const float* __restrict__ rn_b, const float* __restrict__ cn_g,
    const float* __restrict__ cn_b, const float* __restrict__ rtr_W,
    const float* __restrict__ M1, const float* __restrict__ qv,
    const float* __restrict__ cb, const float* __restrict__ temperature,
    float* __restrict__ logitsS) {
  int wid = threadIdx.x >> 6, lane = threadIdx.x & 63;
  int t = blockIdx.x * 4 + wid;
  int d0 = lane * 8;

  float xv[8], cv[8];
  *(float4*)&xv[0] = *(const float4*)(x + (size_t)t * Dd + d0);
  *(float4*)&xv[4] = *(const float4*)(x + (size_t)t * Dd + d0 + 4);
  *(float4*)&cv[0] = *(const float4*)(ctx + (size_t)t * Dd + d0);
  *(float4*)&cv[4] = *(const float4*)(ctx + (size_t)t * Dd + d0 + 4);

  float sx = 0.f, sc = 0.f;
#pragma unroll
  for (int d = 0; d < 8; d++) { sx += xv[d]; sc += cv[d]; }
  float mx = wredx(sx) * (1.f / Dd);
  float mc = wredx(sc) * (1.f / Dd);
  float vx = 0.f, vc = 0.f;
#pragma unroll
  for (int d = 0; d < 8; d++) {
    vx += (xv[d] - mx) * (xv[d] - mx);
    vc += (cv[d] - mc) * (cv[d] - mc);
  }
  float rsx = rsqrtf(wredx(vx) * (1.f / Dd) + 1e-5f);
  float rsc = rsqrtf(wredx(vc) * (1.f / Dd) + 1e-5f);

  float rg[8], rb[8], cg[8], cbb[8];
  *(float4*)&rg[0] = *(const float4*)(rn_g + d0);
  *(float4*)&rg[4] = *(const float4*)(rn_g + d0 + 4);
  *(float4*)&rb[0] = *(const float4*)(rn_b + d0);
  *(float4*)&rb[4] = *(const float4*)(rn_b + d0 + 4);
  *(float4*)&cg[0] = *(const float4*)(cn_g + d0);
  *(float4*)&cg[4] = *(const float4*)(cn_g + d0 + 4);
  *(float4*)&cbb[0] = *(const float4*)(cn_b + d0);
  *(float4*)&cbb[4] = *(const float4*)(cn_b + d0 + 4);

  float lg[Ee] = {0.f, 0.f, 0.f, 0.f, 0.f, 0.f, 0.f, 0.f};
#pragma unroll
  for (int d = 0; d < 8; d++) {
    float xn = (xv[d] - mx) * rsx * rg[d] + rb[d];
    float cn = (cv[d] - mc) * rsc * cg[d] + cbb[d];
    float rw[8], m1[8];
    *(float4*)&rw[0] = *(const float4*)(rtr_W + (size_t)(d0 + d) * Ee);
    *(float4*)&rw[4] = *(const float4*)(rtr_W + (size_t)(d0 + d) * Ee + 4);
    *(float4*)&m1[0] = *(const float4*)(M1 + (size_t)(d0 + d) * Ee);
    *(float4*)&m1[4] = *(const float4*)(M1 + (size_t)(d0 + d) * Ee + 4);
#pragma unroll
    for (int e = 0; e < Ee; e++) lg[e] += xn * rw[e] + cn * m1[e];
  }
#pragma unroll
  for (int e = 0; e < Ee; e++) lg[e] = wredx(lg[e]);

  if (lane == 0) {
    float invT = 1.f / fmaxf(temperature[0], 0.25f);
    float q = quality[t / Ss];
    float L[8];
#pragma unroll
    for (int e = 0; e < Ee; e++) L[e] = (lg[e] + q * qv[e] + cb[e]) * invT;
    *(float4*)(logitsS + (size_t)t * Ee) = *(float4*)&L[0];
    *(float4*)(logitsS + (size_t)t * Ee + 4) = *(float4*)&L[4];
  }
}

// ------------------------------------------------------------------
// Select: ONE block (256 thr), 8 tokens/thread. Top-2, gates, stats
// (register-accumulated, block-reduced), expert lists via LDS atomics.
// Folds offs prefix-sum and aux-scalar finalize.
// ------------------------------------------------------------------
__global__ __launch_bounds__(256) void k_select(
    const float* __restrict__ logitsS, int* __restrict__ cnt,
    int* __restrict__ offs, int* __restrict__ list,
    float* __restrict__ glist, float* __restrict__ out) {
  __shared__ int scnt[Ee];
  __shared__ float s4[4];
  int tid = threadIdx.x;
  if (tid < Ee) scnt[tid] = 0;
  __syncthreads();

  float impL[Ee] = {0.f, 0.f, 0.f, 0.f, 0.f, 0.f, 0.f, 0.f};
  float zL = 0.f, eL = 0.f;

#pragma unroll
  for (int j = 0; j < 8; j++) {
    int t = j * 256 + tid;
    float L[8];
    *(float4*)&L[0] = *(const float4*)(logitsS + (size_t)t * Ee);
    *(float4*)&L[4] = *(const float4*)(logitsS + (size_t)t * Ee + 4);

    int i0 = 0;
#pragma unroll
    for (int e = 1; e < Ee; e++)
      if (L[e] > L[i0]) i0 = e;
    int i1 = (i0 == 0) ? 1 : 0;
#pragma unroll
    for (int e = 0; e < Ee; e++)
      if (e != i0 && L[e] > L[i1]) i1 = e;

    float e1 = __expf(L[i1] - L[i0]);
    float g0 = 1.f / (1.f + e1);
    float g1 = e1 / (1.f + e1);

    float m = L[i0];
    float p[8];
    float sum = 0.f;
#pragma unroll
    for (int e = 0; e < Ee; e++) {
      p[e] = __expf(L[e] - m);
      sum += p[e];
    }
    float lse = m + __logf(sum);
    float inv = 1.f / sum;
    zL += lse * lse;
#pragma unroll
    for (int e = 0; e < Ee; e++) {
      p[e] *= inv;
      eL -= p[e] * __logf(fmaxf(p[e], 1e-9f));
      impL[e] += p[e];
    }

    int s0 = atomicAdd(&scnt[i0], 1);
    list[i0 * CAP + s0] = t;
    glist[i0 * CAP + s0] = g0;
    int s1 = atomicAdd(&scnt[i1], 1);
    list[i1 * CAP + s1] = t;
    glist[i1 * CAP + s1] = g1;
  }

  // block-reduce stats (no global atomics)
  float impS[Ee];
#pragma unroll
  for (int e = 0; e < Ee; e++) impS[e] = block_sum(impL[e], s4, tid);
  float zS = block_sum(zL, s4, tid);
  float eS = block_sum(eL, s4, tid);
  __syncthreads();

  if (tid == 0) {
    int s = 0;
#pragma unroll
    for (int e = 0; e < Ee; e++) {
      cnt[e] = scnt[e];
      offs[e] = s;
      s += scnt[e];
    }
    float lb = 0.f;
#pragma unroll
    for (int e = 0; e < Ee; e++) {
      float v = impS[e] * (1.f / TOKENS) - (1.f / Ee);
      lb += v * v;
    }
    lb *= (1.f / Ee);
    float rz = zS * (1.f / TOKENS);
    float en = eS * (1.f / TOKENS);
    float* sp = out + (size_t)Bb * Ss * Dd;
    sp[0] = lb;
    sp[1] = rz;
    sp[2] = en;
    sp[3] = lb + 0.001f * rz - 0.001f * en;
  }
}

// ------------------------------------------------------------------
// Conversions for MFMA path
// ------------------------------------------------------------------
__global__ __launch_bounds__(256) void k_convx(const float* __restrict__ x,
    ushort* __restrict__ xh, ushort* __restrict__ xl) {
  int i = (blockIdx.x * 256 + threadIdx.x) * 4;
  float4 v = *(const float4*)(x + i);
  ushort4 h, l;
  ushort2 s;
  s = splitbf(v.x); h.x = s.x; l.x = s.y;
  s = splitbf(v.y); h.y = s.x; l.y = s.y;
  s = splitbf(v.z); h.z = s.x; l.z = s.y;
  s = splitbf(v.w); h.w = s.x; l.w = s.y;
  *(ushort4*)(xh + i) = h;
  *(ushort4*)(xl + i) = l;
}

// transpose per expert [R][C] -> [C][R], split into bf16 hi/lo
__global__ __launch_bounds__(256) void k_convT(const float* __restrict__ src,
    ushort* __restrict__ dh, ushort* __restrict__ dl, int R, int C) {
  int nr = R >> 6, ncc = C >> 6;
  int bx = blockIdx.x;
  int e = bx / (nr * ncc);
  int rem = bx % (nr * ncc);
  int rt = rem / ncc, ct = rem % ncc;
  __shared__ float ls[64 * 65];
  int tid = threadIdx.x;
  const float* s0 = src + (size_t)e * R * C + (size_t)(rt * 64) * C + ct * 64;
#pragma unroll
  for (int j = 0; j < 4; j++) {
    int li = j * 256 + tid;
    int rr = li >> 4, c4 = (li & 15) << 2;
    float4 v = *(const float4*)(s0 + (size_t)rr * C + c4);
    ls[rr * 65 + c4] = v.x;
    ls[rr * 65 + c4 + 1] = v.y;
    ls[rr * 65 + c4 + 2] = v.z;
    ls[rr * 65 + c4 + 3] = v.w;
  }
  __syncthreads();
#pragma unroll
  for (int j = 0; j < 4; j++) {
    int li = j * 256 + tid;
    int on = li >> 4, k4 = (li & 15) << 2;
    ushort4 h, l;
    ushort2 s;
    s = splitbf(ls[(k4 + 0) * 65 + on]); h.x = s.x; l.x = s.y;
    s = splitbf(ls[(k4 + 1) * 65 + on]); h.y = s.x; l.y = s.y;
    s = splitbf(ls[(k4 + 2) * 65 + on]); h.z = s.x; l.z = s.y;
    s = splitbf(ls[(k4 + 3) * 65 + on]); h.w = s.x; l.w = s.y;
    size_t p = ((size_t)e * C + ct * 64 + on) * R + rt * 64 + k4;
    *(ushort4*)(dh + p) = h;
    *(ushort4*)(dl + p) = l;
  }
}

// ------------------------------------------------------------------
// MFMA GEMM1: gathered X rows (ne x 512) @ W1[e] (512 x 2048), gelu, split-> hh/hl
// 128x128 tile, BK=32, 4 waves, bf16x3. grid: 8e x 16r x 16c
// ------------------------------------------------------------------
__global__ __launch_bounds__(256) void k_mg1(
    const ushort* __restrict__ xh, const ushort* __restrict__ xl,
    const ushort* __restrict__ w1h, const ushort* __restrict__ w1l,
    const float* __restrict__ b1,
    const int* __restrict__ cnt, const int* __restrict__ offs,
    const int* __restrict__ list,
    ushort* __restrict__ hh, ushort* __restrict__ hl) {
  int bx = blockIdx.x;
  int e = bx >> 8;
  int r = (bx >> 4) & 15;
  int c = bx & 15;
  int ne = cnt[e];
  if (r * 128 >= ne) return;
  int off = offs[e];

  __shared__ ushort As[2][4096];  // [hi/lo][g:4][row:128][8]
  __shared__ ushort Bs[2][4096];
  __shared__ int stok[128];

  int tid = threadIdx.x;
  if (tid < 128) {
    int row = r * 128 + tid;
    stok[tid] = list[e * CAP + ((row < ne) ? row : (ne - 1))];
  }
  __syncthreads();

  int idx0 = tid, idx1 = 256 + tid;
  int g0 = idx0 >> 7, row0 = idx0 & 127;
  int g1 = idx1 >> 7, row1 = idx1 & 127;
  size_t aoff0 = (size_t)stok[row0] * Dd + g0 * 8;
  size_t aoff1 = (size_t)stok[row1] * Dd + g1 * 8;
  size_t boff0 = ((size_t)(e * Hh + c * 128 + row0)) * Dd + g0 * 8;
  size_t boff1 = ((size_t)(e * Hh + c * 128 + row1)) * Dd + g1 * 8;
  ushort* lA0 = &As[0][idx0 * 8]; ushort* lA1 = &As[0][idx1 * 8];
  ushort* lA0l = &As[1][idx0 * 8]; ushort* lA1l = &As[1][idx1 * 8];
  ushort* lB0 = &Bs[0][idx0 * 8]; ushort* lB1 = &Bs[0][idx1 * 8];
  ushort* lB0l = &Bs[1][idx0 * 8]; ushort* lB1l = &Bs[1][idx1 * 8];

  int lane = tid & 63, wid = tid >> 6;
  int wm = wid >> 1, wn = wid & 1;
  int l15 = lane & 15, lg = lane >> 4;

  f32x4 acc[4][4] = {};

  for (int k0 = 0; k0 < Dd; k0 += 32) {
    GL16(xh + aoff0 + k0, lA0);
    GL16(xh + aoff1 + k0, lA1);
    GL16(xl + aoff0 + k0, lA0l);
    GL16(xl + aoff1 + k0, lA1l);
    GL16(w1h + boff0 + k0, lB0);
    GL16(w1h + boff1 + k0, lB1);
    GL16(w1l + boff0 + k0, lB0l);
    GL16(w1l + boff1 + k0, lB1l);
    __syncthreads();

    bf16x8 ah[4], al[4], bh[4], bl[4];
#pragma unroll
    for (int m = 0; m < 4; m++) {
      int o = (lg * 128 + wm * 64 + m * 16 + l15) * 8;
      ah[m] = *(const bf16x8*)&As[0][o];
      al[m] = *(const bf16x8*)&As[1][o];
    }
#pragma unroll
    for (int n = 0; n < 4; n++) {
      int o = (lg * 128 + wn * 64 + n * 16 + l15) * 8;
      bh[n] = *(const bf16x8*)&Bs[0][o];
      bl[n] = *(const bf16x8*)&Bs[1][o];
    }
#pragma unroll
    for (int m = 0; m < 4; m++)
#pragma unroll
      for (int n = 0; n < 4; n++) {
        acc[m][n] = __builtin_amdgcn_mfma_f32_16x16x32_bf16(ah[m], bh[n], acc[m][n], 0, 0, 0);
        acc[m][n] = __builtin_amdgcn_mfma_f32_16x16x32_bf16(ah[m], bl[n], acc[m][n], 0, 0, 0);
        acc[m][n] = __builtin_amdgcn_mfma_f32_16x16x32_bf16(al[m], bh[n], acc[m][n], 0, 0, 0);
      }
    __syncthreads();
  }

  int lg4 = lg * 4;
#pragma unroll
  for (int n = 0; n < 4; n++) {
    int colg = c * 128 + wn * 64 + n * 16 + l15;
    float bias = b1[e * Hh + colg];
#pragma unroll
    for (int m = 0; m < 4; m++) {
#pragma unroll
      for (int j = 0; j < 4; j++) {
        int rowl = r * 128 + wm * 64 + m * 16 + lg4 + j;
        if (rowl < ne) {
          float v = gelu_f(acc[m][n][j] + bias);
          ushort2 s = splitbf(v);
          size_t p = (size_t)(off + rowl) * Hh + colg;
          hh[p] = s.x;
          hl[p] = s.y;
        }
      }
    }
  }
}

// ------------------------------------------------------------------
// MFMA GEMM2: hh/hl rows (ne x 2048) @ W2[e] (2048 x 512), +b2, gate, atomic scatter
// 128x128 tile, BK=32, split-K=2. grid: 8e x 16r x 4c x 2k
// ------------------------------------------------------------------
__global__ __launch_bounds__(256) void k_mg2(
    const ushort* __restrict__ hh, const ushort* __restrict__ hl,
    const ushort* __restrict__ w2h, const ushort* __restrict__ w2l,
    const float* __restrict__ b2,
    const int* __restrict__ cnt, const int* __restrict__ offs,
    const int* __restrict__ list, const float* __restrict__ glist,
    float* __restrict__ out) {
  int bx = blockIdx.x;
  int e = bx >> 7;
  int r = (bx >> 3) & 15;
  int c = (bx >> 1) & 3;
  int kS = bx & 1;
  int ne = cnt[e];
  if (r * 128 >= ne) return;
  int off = offs[e];

  __shared__ ushort As[2][4096];
  __shared__ ushort Bs[2][4096];

  int tid = threadIdx.x;
  int idx0 = tid, idx1 = 256 + tid;
  int g0 = idx0 >> 7, row0 = idx0 & 127;
  int g1 = idx1 >> 7, row1 = idx1 & 127;
  int ar0 = r * 128 + row0; if (ar0 >= ne) ar0 = ne - 1;
  int ar1 = r * 128 + row1; if (ar1 >= ne) ar1 = ne - 1;
  size_t kbase = (size_t)kS * 1024;
  size_t aoff0 = (size_t)(off + ar0) * Hh + kbase + g0 * 8;
  size_t aoff1 = (size_t)(off + ar1) * Hh + kbase + g1 * 8;
  size_t boff0 = ((size_t)(e * Dd + c * 128 + row0)) * Hh + kbase + g0 * 8;
  size_t boff1 = ((size_t)(e * Dd + c * 128 + row1)) * Hh + kbase + g1 * 8;
  ushort* lA0 = &As[0][idx0 * 8]; ushort* lA1 = &As[0][idx1 * 8];
  ushort* lA0l = &As[1][idx0 * 8]; ushort* lA1l = &As[1][idx1 * 8];
  ushort* lB0 = &Bs[0][idx0 * 8]; ushort* lB1 = &Bs[0][idx1 * 8];
  ushort* lB0l = &Bs[1][idx0 * 8]; ushort* lB1l = &Bs[1][idx1 * 8];

  int lane = tid & 63, wid = tid >> 6;
  int wm = wid >> 1, wn = wid & 1;
  int l15 = lane & 15, lg = lane >> 4;

  f32x4 acc[4][4] = {};

  for (int k0 = 0; k0 < 1024; k0 += 32) {
    GL16(hh + aoff0 + k0, lA0);
    GL16(hh + aoff1 + k0, lA1);
    GL16(hl + aoff0 + k0, lA0l);
    GL16(hl + aoff1 + k0, lA1l);
    GL16(w2h + boff0 + k0, lB0);
    GL16(w2h + boff1 + k0, lB1);
    GL16(w2l + boff0 + k0, lB0l);
    GL16(w2l + boff1 + k0, lB1l);
    __syncthreads();

    bf16x8 ah[4], al[4], bh[4], bl[4];
#pragma unroll
    for (int m = 0; m < 4; m++) {
      int o = (lg * 128 + wm * 64 + m * 16 + l15) * 8;
      ah[m] = *(const bf16x8*)&As[0][o];
      al[m] = *(const bf16x8*)&As[1][o];
    }
#pragma unroll
    for (int n = 0; n < 4; n++) {
      int o = (lg * 128 + wn * 64 + n * 16 + l15) * 8;
      bh[n] = *(const bf16x8*)&Bs[0][o];
      bl[n] = *(const bf16x8*)&Bs[1][o];
    }
#pragma unroll
    for (int m = 0; m < 4; m++)
#pragma unroll
      for (int n = 0; n < 4; n++) {
        acc[m][n] = __builtin_amdgcn_mfma_f32_16x16x32_bf16(ah[m], bh[n], acc[m][n], 0, 0, 0);
        acc[m][n] = __builtin_amdgcn_mfma_f32_16x16x32_bf16(ah[m], bl[n], acc[m][n], 0, 0, 0);
        acc[m][n] = __builtin_amdgcn_mfma_f32_16x16x32_bf16(al[m], bh[n], acc[m][n], 0, 0, 0);
      }
    __syncthreads();
  }

  int lg4 = lg * 4;
#pragma unroll
  for (int m = 0; m < 4; m++) {
#pragma unroll
    for (int j = 0; j < 4; j++) {
      int rowl = r * 128 + wm * 64 + m * 16 + lg4 + j;
      if (rowl < ne) {
        int tok = list[e * CAP + rowl];
        float gte = glist[e * CAP + rowl];
#pragma unroll
        for (int n = 0; n < 4; n++) {
          int colg = c * 128 + wn * 64 + n * 16 + l15;
          float v = acc[m][n][j] + (kS == 0 ? b2[e * Dd + colg] : 0.f);
          atomicAdd(&out[(size_t)tok * Dd + colg], gte * v);
        }
      }
    }
  }
}

extern "C" void kernel_launch(void* const* d_in, const int* in_sizes, int n_in,
                              void* d_out, int out_size, void* d_ws, size_t ws_size,
                              hipStream_t stream) {
  const float* x = (const float*)d_in[0];
  const float* ctx = (const float*)d_in[1];
  const float* quality = (const float*)d_in[2];
  const float* rn_g = (const float*)d_in[3];
  const float* rn_b = (const float*)d_in[4];
  const float* cn_g = (const float*)d_in[5];
  const float* cn_b = (const float*)d_in[6];
  const float* ctx_W = (const float*)d_in[7];
  const float* ctx_b = (const float*)d_in[8];
  const float* qual_W = (const float*)d_in[9];
  const float* qual_b = (const float*)d_in[10];
  const float* rtr_W = (const float*)d_in[11];
  const float* rtr_b = (const float*)d_in[12];
  const float* temperature = (const float*)d_in[13];
  const float* W1 = (const float*)d_in[14];
  const float* b1 = (const float*)d_in[15];
  const float* W2 = (const float*)d_in[16];
  const float* b2 = (const float*)d_in[17];
  float* out = (float*)d_out;

  char* w = (char*)d_ws;
  int* cnt = (int*)(w + WS_CNT);
  int* offs = (int*)(w + WS_OFFS);
  float* M1 = (float*)(w + WS_M1);
  float* qv = (float*)(w + WS_QV);
  float* cb = (float*)(w + WS_CB);
  int* list = (int*)(w + WS_LIST);
  float* glist = (float*)(w + WS_GLIST);
  float* logitsS = (float*)(w + WS_LOG);
  ushort* xh = (ushort*)(w + WS_XH);
  ushort* xl = (ushort*)(w + WS_XL);
  ushort* w1h = (ushort*)(w + WS_W1H);
  ushort* w1l = (ushort*)(w + WS_W1L);
  ushort* w2h = (ushort*)(w + WS_W2H);
  ushort* w2l = (ushort*)(w + WS_W2L);
  ushort* hh = (ushort*)(w + WS_HH);
  ushort* hl = (ushort*)(w + WS_HL);

  hipMemsetAsync(d_out, 0, (size_t)out_size * sizeof(float), stream);

  k_precomp<<<513, 64, 0, stream>>>(ctx_W, rtr_W, rtr_b, qual_W, qual_b, ctx_b, M1, qv, cb);
  k_logits<<<TOKENS / 4, 256, 0, stream>>>(x, ctx, quality, rn_g, rn_b, cn_g, cn_b, rtr_W,
                                           M1, qv, cb, temperature, logitsS);
  k_convx<<<1024, 256, 0, stream>>>(x, xh, xl);
  k_convT<<<Ee * 8 * 32, 256, 0, stream>>>(W1, w1h, w1l, Dd, Hh);
  k_convT<<<Ee * 32 * 8, 256, 0, stream>>>(W2, w2h, w2l, Hh, Dd);
  k_select<<<1, 256, 0, stream>>>(logitsS, cnt, offs, list, glist, out);
  k_mg1<<<Ee * 16 * 16, 256, 0, stream>>>(xh, xl, w1h, w1l, b1, cnt, offs, list, hh, hl);
  k_mg2<<<Ee * 16 * 4 * 2, 256, 0, stream>>>(hh, hl, w2h, w2l, b2, cnt, offs, list, glist, out);
}

// Round 4
// 297.743 us; speedup vs baseline: 2.9496x; 1.2575x over previous
//
#include <hip/hip_runtime.h>
#include <hip/hip_bf16.h>
#include <math.h>

#define Bb 4
#define Ss 512
#define Dd 512
#define Hh 2048
#define Ee 8
#define TOKENS 2048
#define CAP 2048

typedef __attribute__((ext_vector_type(8))) _Float16 f16x8;
typedef __attribute__((ext_vector_type(4))) _Float16 f16x4;
typedef __attribute__((ext_vector_type(4))) float f32x4;

// ---------------- ws layout (bytes) ----------------
#define WS_CNT   0
#define WS_OFFS  32
#define WS_M1    128
#define WS_QV    16512
#define WS_CB    16544
#define WS_LIST  16640
#define WS_GLIST 82176
#define WS_LOG   147712                 // float logits[2048][8]
#define WS_XF    (WS_LOG + 65536)       // fp16 x [2048][512]   (2 MB)
#define WS_W1F   (WS_XF + 2097152)      // fp16 W1^T [8][2048][512] (16 MB)
#define WS_W2F   (WS_W1F + 16777216)    // fp16 W2^T [8][512][2048] (16 MB)
#define WS_HF    (WS_W2F + 16777216)    // fp16 h [4096][2048] (16 MB)

__device__ __forceinline__ float wred(float v) {
#pragma unroll
  for (int o = 32; o > 0; o >>= 1) v += __shfl_down(v, o);
  return v;
}

__device__ __forceinline__ float wredx(float v) {
#pragma unroll
  for (int o = 32; o > 0; o >>= 1) v += __shfl_xor(v, o);
  return v;
}

__device__ __forceinline__ float block_sum(float v, float* s4, int tid) {
  v = wred(v);
  __syncthreads();
  if ((tid & 63) == 0) s4[tid >> 6] = v;
  __syncthreads();
  return s4[0] + s4[1] + s4[2] + s4[3];
}

__device__ __forceinline__ float gelu_f(float v) {
  return 0.5f * v * (1.0f + erff(v * 0.7071067811865475f));
}

#define GL16(gp, lp) __builtin_amdgcn_global_load_lds( \
    (const __attribute__((address_space(1))) void*)(gp), \
    (__attribute__((address_space(3))) void*)(lp), 16, 0, 0)

// ------------------------------------------------------------------
// Precompute M1 = ctx_W @ rtr_W, qv = qual_W@rtr_W, cb = (ctx_b+qual_b)@rtr_W + rtr_b
// ------------------------------------------------------------------
__global__ __launch_bounds__(64) void k_precomp(
    const float* __restrict__ ctx_W, const float* __restrict__ rtr_W,
    const float* __restrict__ rtr_b, const float* __restrict__ qual_W,
    const float* __restrict__ qual_b, const float* __restrict__ ctx_b,
    float* __restrict__ M1, float* __restrict__ qv, float* __restrict__ cb) {
  int d = blockIdx.x;
  int lane = threadIdx.x;
  if (d < Dd) {
    float acc[Ee] = {0.f, 0.f, 0.f, 0.f, 0.f, 0.f, 0.f, 0.f};
    for (int k = lane; k < Dd; k += 64) {
      float cw = ctx_W[d * Dd + k];
      const float* r = rtr_W + k * Ee;
#pragma unroll
      for (int e = 0; e < Ee; e++) acc[e] += cw * r[e];
    }
#pragma unroll
    for (int e = 0; e < Ee; e++) acc[e] = wred(acc[e]);
    if (lane == 0) {
#pragma unroll
      for (int e = 0; e < Ee; e++) M1[d * Ee + e] = acc[e];
    }
  } else {
    float aq[Ee] = {0.f, 0.f, 0.f, 0.f, 0.f, 0.f, 0.f, 0.f};
    float ab[Ee] = {0.f, 0.f, 0.f, 0.f, 0.f, 0.f, 0.f, 0.f};
    for (int k = lane; k < Dd; k += 64) {
      float qw = qual_W[k];
      float bb = ctx_b[k] + qual_b[k];
      const float* r = rtr_W + k * Ee;
#pragma unroll
      for (int e = 0; e < Ee; e++) {
        aq[e] += qw * r[e];
        ab[e] += bb * r[e];
      }
    }
#pragma unroll
    for (int e = 0; e < Ee; e++) {
      aq[e] = wred(aq[e]);
      ab[e] = wred(ab[e]);
    }
    if (lane == 0) {
#pragma unroll
      for (int e = 0; e < Ee; e++) {
        qv[e] = aq[e];
        cb[e] = ab[e] + rtr_b[e];
      }
    }
  }
}

// ------------------------------------------------------------------
// Logits + x->fp16: one wave per token.
// ------------------------------------------------------------------
__global__ __launch_bounds__(256) void k_logits(
    const float* __restrict__ x, const float* __restrict__ ctx,
    const float* __restrict__ quality, const float* __restrict__ rn_g,
    const float* __restrict__ rn_b, const float* __restrict__ cn_g,
    const float* __restrict__ cn_b, const float* __restrict__ rtr_W,
    const float* __restrict__ M1, const float* __restrict__ qv,
    const float* __restrict__ cb, const float* __restrict__ temperature,
    float* __restrict__ logitsS, _Float16* __restrict__ xf) {
  int wid = threadIdx.x >> 6, lane = threadIdx.x & 63;
  int t = blockIdx.x * 4 + wid;
  int d0 = lane * 8;

  float xv[8], cv[8];
  *(float4*)&xv[0] = *(const float4*)(x + (size_t)t * Dd + d0);
  *(float4*)&xv[4] = *(const float4*)(x + (size_t)t * Dd + d0 + 4);
  *(float4*)&cv[0] = *(const float4*)(ctx + (size_t)t * Dd + d0);
  *(float4*)&cv[4] = *(const float4*)(ctx + (size_t)t * Dd + d0 + 4);

  // x -> fp16 for the FFN
  f16x8 xh;
#pragma unroll
  for (int d = 0; d < 8; d++) xh[d] = (_Float16)xv[d];
  *(f16x8*)(xf + (size_t)t * Dd + d0) = xh;

  float sx = 0.f, sc = 0.f;
#pragma unroll
  for (int d = 0; d < 8; d++) { sx += xv[d]; sc += cv[d]; }
  float mx = wredx(sx) * (1.f / Dd);
  float mc = wredx(sc) * (1.f / Dd);
  float vx = 0.f, vc = 0.f;
#pragma unroll
  for (int d = 0; d < 8; d++) {
    vx += (xv[d] - mx) * (xv[d] - mx);
    vc += (cv[d] - mc) * (cv[d] - mc);
  }
  float rsx = rsqrtf(wredx(vx) * (1.f / Dd) + 1e-5f);
  float rsc = rsqrtf(wredx(vc) * (1.f / Dd) + 1e-5f);

  float rg[8], rb[8], cg[8], cbb[8];
  *(float4*)&rg[0] = *(const float4*)(rn_g + d0);
  *(float4*)&rg[4] = *(const float4*)(rn_g + d0 + 4);
  *(float4*)&rb[0] = *(const float4*)(rn_b + d0);
  *(float4*)&rb[4] = *(const float4*)(rn_b + d0 + 4);
  *(float4*)&cg[0] = *(const float4*)(cn_g + d0);
  *(float4*)&cg[4] = *(const float4*)(cn_g + d0 + 4);
  *(float4*)&cbb[0] = *(const float4*)(cn_b + d0);
  *(float4*)&cbb[4] = *(const float4*)(cn_b + d0 + 4);

  float lg[Ee] = {0.f, 0.f, 0.f, 0.f, 0.f, 0.f, 0.f, 0.f};
#pragma unroll
  for (int d = 0; d < 8; d++) {
    float xn = (xv[d] - mx) * rsx * rg[d] + rb[d];
    float cn = (cv[d] - mc) * rsc * cg[d] + cbb[d];
    float rw[8], m1[8];
    *(float4*)&rw[0] = *(const float4*)(rtr_W + (size_t)(d0 + d) * Ee);
    *(float4*)&rw[4] = *(const float4*)(rtr_W + (size_t)(d0 + d) * Ee + 4);
    *(float4*)&m1[0] = *(const float4*)(M1 + (size_t)(d0 + d) * Ee);
    *(float4*)&m1[4] = *(const float4*)(M1 + (size_t)(d0 + d) * Ee + 4);
#pragma unroll
    for (int e = 0; e < Ee; e++) lg[e] += xn * rw[e] + cn * m1[e];
  }
#pragma unroll
  for (int e = 0; e < Ee; e++) lg[e] = wredx(lg[e]);

  if (lane == 0) {
    float invT = 1.f / fmaxf(temperature[0], 0.25f);
    float q = quality[t / Ss];
    float L[8];
#pragma unroll
    for (int e = 0; e < Ee; e++) L[e] = (lg[e] + q * qv[e] + cb[e]) * invT;
    *(float4*)(logitsS + (size_t)t * Ee) = *(float4*)&L[0];
    *(float4*)(logitsS + (size_t)t * Ee + 4) = *(float4*)&L[4];
  }
}

// ------------------------------------------------------------------
// Select: ONE block, top-2 + gates + stats + lists. No global atomics.
// ------------------------------------------------------------------
__global__ __launch_bounds__(256) void k_select(
    const float* __restrict__ logitsS, int* __restrict__ cnt,
    int* __restrict__ offs, int* __restrict__ list,
    float* __restrict__ glist, float* __restrict__ out) {
  __shared__ int scnt[Ee];
  __shared__ float s4[4];
  int tid = threadIdx.x;
  if (tid < Ee) scnt[tid] = 0;
  __syncthreads();

  float impL[Ee] = {0.f, 0.f, 0.f, 0.f, 0.f, 0.f, 0.f, 0.f};
  float zL = 0.f, eL = 0.f;

#pragma unroll
  for (int j = 0; j < 8; j++) {
    int t = j * 256 + tid;
    float L[8];
    *(float4*)&L[0] = *(const float4*)(logitsS + (size_t)t * Ee);
    *(float4*)&L[4] = *(const float4*)(logitsS + (size_t)t * Ee + 4);

    int i0 = 0;
#pragma unroll
    for (int e = 1; e < Ee; e++)
      if (L[e] > L[i0]) i0 = e;
    int i1 = (i0 == 0) ? 1 : 0;
#pragma unroll
    for (int e = 0; e < Ee; e++)
      if (e != i0 && L[e] > L[i1]) i1 = e;

    float e1 = __expf(L[i1] - L[i0]);
    float g0 = 1.f / (1.f + e1);
    float g1 = e1 / (1.f + e1);

    float m = L[i0];
    float p[8];
    float sum = 0.f;
#pragma unroll
    for (int e = 0; e < Ee; e++) {
      p[e] = __expf(L[e] - m);
      sum += p[e];
    }
    float lse = m + __logf(sum);
    float inv = 1.f / sum;
    zL += lse * lse;
#pragma unroll
    for (int e = 0; e < Ee; e++) {
      p[e] *= inv;
      eL -= p[e] * __logf(fmaxf(p[e], 1e-9f));
      impL[e] += p[e];
    }

    int s0 = atomicAdd(&scnt[i0], 1);
    list[i0 * CAP + s0] = t;
    glist[i0 * CAP + s0] = g0;
    int s1 = atomicAdd(&scnt[i1], 1);
    list[i1 * CAP + s1] = t;
    glist[i1 * CAP + s1] = g1;
  }

  float impS[Ee];
#pragma unroll
  for (int e = 0; e < Ee; e++) impS[e] = block_sum(impL[e], s4, tid);
  float zS = block_sum(zL, s4, tid);
  float eS = block_sum(eL, s4, tid);
  __syncthreads();

  if (tid == 0) {
    int s = 0;
#pragma unroll
    for (int e = 0; e < Ee; e++) {
      cnt[e] = scnt[e];
      offs[e] = s;
      s += scnt[e];
    }
    float lb = 0.f;
#pragma unroll
    for (int e = 0; e < Ee; e++) {
      float v = impS[e] * (1.f / TOKENS) - (1.f / Ee);
      lb += v * v;
    }
    lb *= (1.f / Ee);
    float rz = zS * (1.f / TOKENS);
    float en = eS * (1.f / TOKENS);
    float* sp = out + (size_t)Bb * Ss * Dd;
    sp[0] = lb;
    sp[1] = rz;
    sp[2] = en;
    sp[3] = lb + 0.001f * rz - 0.001f * en;
  }
}

// ------------------------------------------------------------------
// Weight transpose + fp32->fp16: W1 [D][H]->[H][D], W2 [H][D]->[D][H], per expert.
// One merged launch: bx < 2048 -> W1 tiles, else W2 tiles.
// ------------------------------------------------------------------
__device__ __forceinline__ void convT_tile(const float* __restrict__ src,
    _Float16* __restrict__ dst, int R, int C, int bx, float* ls) {
  int nr = R >> 6, ncc = C >> 6;
  int e = bx / (nr * ncc);
  int rem = bx % (nr * ncc);
  int rt = rem / ncc, ct = rem % ncc;
  int tid = threadIdx.x;
  const float* s0 = src + (size_t)e * R * C + (size_t)(rt * 64) * C + ct * 64;
#pragma unroll
  for (int j = 0; j < 4; j++) {
    int li = j * 256 + tid;
    int rr = li >> 4, c4 = (li & 15) << 2;
    float4 v = *(const float4*)(s0 + (size_t)rr * C + c4);
    ls[rr * 65 + c4] = v.x;
    ls[rr * 65 + c4 + 1] = v.y;
    ls[rr * 65 + c4 + 2] = v.z;
    ls[rr * 65 + c4 + 3] = v.w;
  }
  __syncthreads();
#pragma unroll
  for (int j = 0; j < 4; j++) {
    int li = j * 256 + tid;
    int on = li >> 4, k4 = (li & 15) << 2;
    f16x4 o;
    o[0] = (_Float16)ls[(k4 + 0) * 65 + on];
    o[1] = (_Float16)ls[(k4 + 1) * 65 + on];
    o[2] = (_Float16)ls[(k4 + 2) * 65 + on];
    o[3] = (_Float16)ls[(k4 + 3) * 65 + on];
    *(f16x4*)(dst + ((size_t)e * C + ct * 64 + on) * R + rt * 64 + k4) = o;
  }
}

__global__ __launch_bounds__(256) void k_convW(
    const float* __restrict__ W1, const float* __restrict__ W2,
    _Float16* __restrict__ w1f, _Float16* __restrict__ w2f) {
  __shared__ float ls[64 * 65];
  int bx = blockIdx.x;
  if (bx < Ee * 8 * 32) {
    convT_tile(W1, w1f, Dd, Hh, bx, ls);
  } else {
    convT_tile(W2, w2f, Hh, Dd, bx - Ee * 8 * 32, ls);
  }
}

// ------------------------------------------------------------------
// GEMM1 fp16: gathered X (ne x 512) @ W1[e] (512 x 2048), gelu -> hf
// BM=64, BN=128, BK=32, double-buffered prefetch. grid: 8e x 32r x 16c
// ------------------------------------------------------------------
__global__ __launch_bounds__(256) void k_mg1(
    const _Float16* __restrict__ xf, const _Float16* __restrict__ w1f,
    const float* __restrict__ b1,
    const int* __restrict__ cnt, const int* __restrict__ offs,
    const int* __restrict__ list, _Float16* __restrict__ hf) {
  int bx = blockIdx.x;
  int e = bx >> 9;
  int r = (bx >> 4) & 31;
  int c = bx & 15;
  int ne = cnt[e];
  if (r * 64 >= ne) return;
  int off = offs[e];

  __shared__ _Float16 As[2][4 * 64 * 8];    // 4 KB x2
  __shared__ _Float16 Bs[2][4 * 128 * 8];   // 8 KB x2
  __shared__ int stok[64];

  int tid = threadIdx.x;
  if (tid < 64) {
    int row = r * 64 + tid;
    stok[tid] = list[e * CAP + ((row < ne) ? row : (ne - 1))];
  }
  __syncthreads();

  int ag = tid >> 6, arow = tid & 63;
  size_t asrc = (size_t)stok[arow] * Dd + ag * 8;
  int bg0 = tid >> 7, brow0 = tid & 127;
  size_t bsrc0 = ((size_t)(e * Hh + c * 128 + brow0)) * Dd + bg0 * 8;
  size_t bsrc1 = bsrc0 + 16;  // g += 2
  int aL = (ag * 64 + arow) * 8;
  int bL0 = (bg0 * 128 + brow0) * 8;
  int bL1 = ((bg0 + 2) * 128 + brow0) * 8;

  int lane = tid & 63, wid = tid >> 6;
  int wm = wid >> 1, wn = wid & 1;
  int l15 = lane & 15, lg = lane >> 4;

  f32x4 acc[2][4] = {};

  GL16(xf + asrc, &As[0][aL]);
  GL16(w1f + bsrc0, &Bs[0][bL0]);
  GL16(w1f + bsrc1, &Bs[0][bL1]);
  __syncthreads();

  int cur = 0;
  for (int k0 = 32; k0 <= Dd; k0 += 32) {
    if (k0 < Dd) {
      GL16(xf + asrc + k0, &As[cur ^ 1][aL]);
      GL16(w1f + bsrc0 + k0, &Bs[cur ^ 1][bL0]);
      GL16(w1f + bsrc1 + k0, &Bs[cur ^ 1][bL1]);
    }
    f16x8 a[2], b[4];
#pragma unroll
    for (int m = 0; m < 2; m++)
      a[m] = *(const f16x8*)&As[cur][(lg * 64 + wm * 32 + m * 16 + l15) * 8];
#pragma unroll
    for (int n = 0; n < 4; n++)
      b[n] = *(const f16x8*)&Bs[cur][(lg * 128 + wn * 64 + n * 16 + l15) * 8];
#pragma unroll
    for (int m = 0; m < 2; m++)
#pragma unroll
      for (int n = 0; n < 4; n++)
        acc[m][n] = __builtin_amdgcn_mfma_f32_16x16x32_f16(a[m], b[n], acc[m][n], 0, 0, 0);
    __syncthreads();
    cur ^= 1;
  }

  int lg4 = lg * 4;
#pragma unroll
  for (int n = 0; n < 4; n++) {
    int colg = c * 128 + wn * 64 + n * 16 + l15;
    float bias = b1[e * Hh + colg];
#pragma unroll
    for (int m = 0; m < 2; m++) {
#pragma unroll
      for (int j = 0; j < 4; j++) {
        int rowl = r * 64 + wm * 32 + m * 16 + lg4 + j;
        if (rowl < ne)
          hf[(size_t)(off + rowl) * Hh + colg] = (_Float16)gelu_f(acc[m][n][j] + bias);
      }
    }
  }
}

// ------------------------------------------------------------------
// GEMM2 fp16: hf (ne x 2048) @ W2[e] (2048 x 512), +b2, gate, atomic scatter
// BM=64, BN=128, BK=32, split-K=2, dbuf. grid: 8e x 32r x 4c x 2k
// ------------------------------------------------------------------
__global__ __launch_bounds__(256) void k_mg2(
    const _Float16* __restrict__ hf, const _Float16* __restrict__ w2f,
    const float* __restrict__ b2,
    const int* __restrict__ cnt, const int* __restrict__ offs,
    const int* __restrict__ list, const float* __restrict__ glist,
    float* __restrict__ out) {
  int bx = blockIdx.x;
  int e = bx >> 8;
  int r = (bx >> 3) & 31;
  int c = (bx >> 1) & 3;
  int kS = bx & 1;
  int ne = cnt[e];
  if (r * 64 >= ne) return;
  int off = offs[e];

  __shared__ _Float16 As[2][4 * 64 * 8];
  __shared__ _Float16 Bs[2][4 * 128 * 8];

  int tid = threadIdx.x;
  int ag = tid >> 6, arow = tid & 63;
  int ar = r * 64 + arow;
  if (ar >= ne) ar = ne - 1;
  size_t kb = (size_t)kS * 1024;
  size_t asrc = (size_t)(off + ar) * Hh + kb + ag * 8;
  int bg0 = tid >> 7, brow0 = tid & 127;
  size_t bsrc0 = ((size_t)(e * Dd + c * 128 + brow0)) * Hh + kb + bg0 * 8;
  size_t bsrc1 = bsrc0 + 16;
  int aL = (ag * 64 + arow) * 8;
  int bL0 = (bg0 * 128 + brow0) * 8;
  int bL1 = ((bg0 + 2) * 128 + brow0) * 8;

  int lane = tid & 63, wid = tid >> 6;
  int wm = wid >> 1, wn = wid & 1;
  int l15 = lane & 15, lg = lane >> 4;

  f32x4 acc[2][4] = {};

  GL16(hf + asrc, &As[0][aL]);
  GL16(w2f + bsrc0, &Bs[0][bL0]);
  GL16(w2f + bsrc1, &Bs[0][bL1]);
  __syncthreads();

  int cur = 0;
  for (int k0 = 32; k0 <= 1024; k0 += 32) {
    if (k0 < 1024) {
      GL16(hf + asrc + k0, &As[cur ^ 1][aL]);
      GL16(w2f + bsrc0 + k0, &Bs[cur ^ 1][bL0]);
      GL16(w2f + bsrc1 + k0, &Bs[cur ^ 1][bL1]);
    }
    f16x8 a[2], b[4];
#pragma unroll
    for (int m = 0; m < 2; m++)
      a[m] = *(const f16x8*)&As[cur][(lg * 64 + wm * 32 + m * 16 + l15) * 8];
#pragma unroll
    for (int n = 0; n < 4; n++)
      b[n] = *(const f16x8*)&Bs[cur][(lg * 128 + wn * 64 + n * 16 + l15) * 8];
#pragma unroll
    for (int m = 0; m < 2; m++)
#pragma unroll
      for (int n = 0; n < 4; n++)
        acc[m][n] = __builtin_amdgcn_mfma_f32_16x16x32_f16(a[m], b[n], acc[m][n], 0, 0, 0);
    __syncthreads();
    cur ^= 1;
  }

  int lg4 = lg * 4;
#pragma unroll
  for (int m = 0; m < 2; m++) {
#pragma unroll
    for (int j = 0; j < 4; j++) {
      int rowl = r * 64 + wm * 32 + m * 16 + lg4 + j;
      if (rowl < ne) {
        int tok = list[e * CAP + rowl];
        float gte = glist[e * CAP + rowl];
#pragma unroll
        for (int n = 0; n < 4; n++) {
          int colg = c * 128 + wn * 64 + n * 16 + l15;
          float v = acc[m][n][j] + (kS == 0 ? b2[e * Dd + colg] : 0.f);
          atomicAdd(&out[(size_t)tok * Dd + colg], gte * v);
        }
      }
    }
  }
}

extern "C" void kernel_launch(void* const* d_in, const int* in_sizes, int n_in,
                              void* d_out, int out_size, void* d_ws, size_t ws_size,
                              hipStream_t stream) {
  const float* x = (const float*)d_in[0];
  const float* ctx = (const float*)d_in[1];
  const float* quality = (const float*)d_in[2];
  const float* rn_g = (const float*)d_in[3];
  const float* rn_b = (const float*)d_in[4];
  const float* cn_g = (const float*)d_in[5];
  const float* cn_b = (const float*)d_in[6];
  const float* ctx_W = (const float*)d_in[7];
  const float* ctx_b = (const float*)d_in[8];
  const float* qual_W = (const float*)d_in[9];
  const float* qual_b = (const float*)d_in[10];
  const float* rtr_W = (const float*)d_in[11];
  const float* rtr_b = (const float*)d_in[12];
  const float* temperature = (const float*)d_in[13];
  const float* W1 = (const float*)d_in[14];
  const float* b1 = (const float*)d_in[15];
  const float* W2 = (const float*)d_in[16];
  const float* b2 = (const float*)d_in[17];
  float* out = (float*)d_out;

  char* w = (char*)d_ws;
  int* cnt = (int*)(w + WS_CNT);
  int* offs = (int*)(w + WS_OFFS);
  float* M1 = (float*)(w + WS_M1);
  float* qv = (float*)(w + WS_QV);
  float* cb = (float*)(w + WS_CB);
  int* list = (int*)(w + WS_LIST);
  float* glist = (float*)(w + WS_GLIST);
  float* logitsS = (float*)(w + WS_LOG);
  _Float16* xf = (_Float16*)(w + WS_XF);
  _Float16* w1f = (_Float16*)(w + WS_W1F);
  _Float16* w2f = (_Float16*)(w + WS_W2F);
  _Float16* hf = (_Float16*)(w + WS_HF);

  hipMemsetAsync(d_out, 0, (size_t)out_size * sizeof(float), stream);

  k_precomp<<<513, 64, 0, stream>>>(ctx_W, rtr_W, rtr_b, qual_W, qual_b, ctx_b, M1, qv, cb);
  k_logits<<<TOKENS / 4, 256, 0, stream>>>(x, ctx, quality, rn_g, rn_b, cn_g, cn_b, rtr_W,
                                           M1, qv, cb, temperature, logitsS, xf);
  k_convW<<<Ee * 8 * 32 * 2, 256, 0, stream>>>(W1, W2, w1f, w2f);
  k_select<<<1, 256, 0, stream>>>(logitsS, cnt, offs, list, glist, out);
  k_mg1<<<Ee * 32 * 16, 256, 0, stream>>>(xf, w1f, b1, cnt, offs, list, hf);
  k_mg2<<<Ee * 32 * 4 * 2, 256, 0, stream>>>(hf, w2f, b2, cnt, offs, list, glist, out);
}

// Round 6
// 271.892 us; speedup vs baseline: 3.2300x; 1.0951x over previous
//
#include <hip/hip_runtime.h>
#include <hip/hip_bf16.h>
#include <math.h>

#define Bb 4
#define Ss 512
#define Dd 512
#define Hh 2048
#define Ee 8
#define TOKENS 2048
#define CAP 2048

typedef __attribute__((ext_vector_type(8))) _Float16 f16x8;
typedef __attribute__((ext_vector_type(4))) _Float16 f16x4;
typedef __attribute__((ext_vector_type(4))) float f32x4;

// ---------------- ws layout (bytes) ----------------
#define WS_CNT   0
#define WS_OFFS  32
#define WS_M1    128
#define WS_QV    16512
#define WS_CB    16544
#define WS_LIST  16640
#define WS_GLIST 82176
#define WS_LOG   147712                 // float logits[2048][8]
#define WS_XF    (WS_LOG + 65536)       // fp16 x [2048][512]   (2 MB)
#define WS_W1F   (WS_XF + 2097152)      // fp16 W1^T [8][2048][512] (16 MB)
#define WS_W2F   (WS_W1F + 16777216)    // fp16 W2^T [8][512][2048] (16 MB)
#define WS_HF    (WS_W2F + 16777216)    // fp16 h [4096][2048] (16 MB)

__device__ __forceinline__ float wred(float v) {
#pragma unroll
  for (int o = 32; o > 0; o >>= 1) v += __shfl_down(v, o);
  return v;
}

__device__ __forceinline__ float wredx(float v) {
#pragma unroll
  for (int o = 32; o > 0; o >>= 1) v += __shfl_xor(v, o);
  return v;
}

__device__ __forceinline__ float block_sum(float v, float* s4, int tid) {
  v = wred(v);
  __syncthreads();
  if ((tid & 63) == 0) s4[tid >> 6] = v;
  __syncthreads();
  return s4[0] + s4[1] + s4[2] + s4[3];
}

__device__ __forceinline__ float gelu_f(float v) {
  return 0.5f * v * (1.0f + erff(v * 0.7071067811865475f));
}

#define GL16(gp, lp) __builtin_amdgcn_global_load_lds( \
    (const __attribute__((address_space(1))) void*)(gp), \
    (__attribute__((address_space(3))) void*)(lp), 16, 0, 0)

// ------------------------------------------------------------------
// Merged: precomp (blocks 0..512) + weight transpose/convert (rest).
// precomp: M1 = ctx_W @ rtr_W, qv = qual_W@rtr_W, cb = (ctx_b+qual_b)@rtr_W + rtr_b
// convW: W1 [D][H]->[H][D] fp16, W2 [H][D]->[D][H] fp16, per expert.
// ------------------------------------------------------------------
__device__ __forceinline__ void convT_tile(const float* __restrict__ src,
    _Float16* __restrict__ dst, int R, int C, int bx, float* ls) {
  int nr = R >> 6, ncc = C >> 6;
  int e = bx / (nr * ncc);
  int rem = bx % (nr * ncc);
  int rt = rem / ncc, ct = rem % ncc;
  int tid = threadIdx.x;
  const float* s0 = src + (size_t)e * R * C + (size_t)(rt * 64) * C + ct * 64;
#pragma unroll
  for (int j = 0; j < 4; j++) {
    int li = j * 256 + tid;
    int rr = li >> 4, c4 = (li & 15) << 2;
    float4 v = *(const float4*)(s0 + (size_t)rr * C + c4);
    ls[rr * 65 + c4] = v.x;
    ls[rr * 65 + c4 + 1] = v.y;
    ls[rr * 65 + c4 + 2] = v.z;
    ls[rr * 65 + c4 + 3] = v.w;
  }
  __syncthreads();
#pragma unroll
  for (int j = 0; j < 4; j++) {
    int li = j * 256 + tid;
    int on = li >> 4, k4 = (li & 15) << 2;
    f16x4 o;
    o[0] = (_Float16)ls[(k4 + 0) * 65 + on];
    o[1] = (_Float16)ls[(k4 + 1) * 65 + on];
    o[2] = (_Float16)ls[(k4 + 2) * 65 + on];
    o[3] = (_Float16)ls[(k4 + 3) * 65 + on];
    *(f16x4*)(dst + ((size_t)e * C + ct * 64 + on) * R + rt * 64 + k4) = o;
  }
}

__global__ __launch_bounds__(256) void k_pre(
    const float* __restrict__ ctx_W, const float* __restrict__ rtr_W,
    const float* __restrict__ rtr_b, const float* __restrict__ qual_W,
    const float* __restrict__ qual_b, const float* __restrict__ ctx_b,
    const float* __restrict__ W1, const float* __restrict__ W2,
    float* __restrict__ M1, float* __restrict__ qv, float* __restrict__ cb,
    _Float16* __restrict__ w1f, _Float16* __restrict__ w2f) {
  __shared__ float ls[64 * 65];
  int bx = blockIdx.x;
  if (bx >= 513) {
    int cx = bx - 513;
    if (cx < Ee * 8 * 32) convT_tile(W1, w1f, Dd, Hh, cx, ls);
    else convT_tile(W2, w2f, Hh, Dd, cx - Ee * 8 * 32, ls);
    return;
  }
  int d = bx;
  int tid = threadIdx.x;
  if (tid >= 64) return;
  int lane = tid;
  if (d < Dd) {
    float acc[Ee] = {0.f, 0.f, 0.f, 0.f, 0.f, 0.f, 0.f, 0.f};
    for (int k = lane; k < Dd; k += 64) {
      float cw = ctx_W[d * Dd + k];
      const float* r = rtr_W + k * Ee;
#pragma unroll
      for (int e = 0; e < Ee; e++) acc[e] += cw * r[e];
    }
#pragma unroll
    for (int e = 0; e < Ee; e++) acc[e] = wred(acc[e]);
    if (lane == 0) {
#pragma unroll
      for (int e = 0; e < Ee; e++) M1[d * Ee + e] = acc[e];
    }
  } else {
    float aq[Ee] = {0.f, 0.f, 0.f, 0.f, 0.f, 0.f, 0.f, 0.f};
    float ab[Ee] = {0.f, 0.f, 0.f, 0.f, 0.f, 0.f, 0.f, 0.f};
    for (int k = lane; k < Dd; k += 64) {
      float qw = qual_W[k];
      float bb = ctx_b[k] + qual_b[k];
      const float* r = rtr_W + k * Ee;
#pragma unroll
      for (int e = 0; e < Ee; e++) {
        aq[e] += qw * r[e];
        ab[e] += bb * r[e];
      }
    }
#pragma unroll
    for (int e = 0; e < Ee; e++) {
      aq[e] = wred(aq[e]);
      ab[e] = wred(ab[e]);
    }
    if (lane == 0) {
#pragma unroll
      for (int e = 0; e < Ee; e++) {
        qv[e] = aq[e];
        cb[e] = ab[e] + rtr_b[e];
      }
    }
  }
}

// ------------------------------------------------------------------
// Logits + x->fp16: one wave per token.
// ------------------------------------------------------------------
__global__ __launch_bounds__(256) void k_logits(
    const float* __restrict__ x, const float* __restrict__ ctx,
    const float* __restrict__ quality, const float* __restrict__ rn_g,
    const float* __restrict__ rn_b, const float* __restrict__ cn_g,
    const float* __restrict__ cn_b, const float* __restrict__ rtr_W,
    const float* __restrict__ M1, const float* __restrict__ qv,
    const float* __restrict__ cb, const float* __restrict__ temperature,
    float* __restrict__ logitsS, _Float16* __restrict__ xf) {
  int wid = threadIdx.x >> 6, lane = threadIdx.x & 63;
  int t = blockIdx.x * 4 + wid;
  int d0 = lane * 8;

  float xv[8], cv[8];
  *(float4*)&xv[0] = *(const float4*)(x + (size_t)t * Dd + d0);
  *(float4*)&xv[4] = *(const float4*)(x + (size_t)t * Dd + d0 + 4);
  *(float4*)&cv[0] = *(const float4*)(ctx + (size_t)t * Dd + d0);
  *(float4*)&cv[4] = *(const float4*)(ctx + (size_t)t * Dd + d0 + 4);

  f16x8 xh;
#pragma unroll
  for (int d = 0; d < 8; d++) xh[d] = (_Float16)xv[d];
  *(f16x8*)(xf + (size_t)t * Dd + d0) = xh;

  float sx = 0.f, sc = 0.f;
#pragma unroll
  for (int d = 0; d < 8; d++) { sx += xv[d]; sc += cv[d]; }
  float mx = wredx(sx) * (1.f / Dd);
  float mc = wredx(sc) * (1.f / Dd);
  float vx = 0.f, vc = 0.f;
#pragma unroll
  for (int d = 0; d < 8; d++) {
    vx += (xv[d] - mx) * (xv[d] - mx);
    vc += (cv[d] - mc) * (cv[d] - mc);
  }
  float rsx = rsqrtf(wredx(vx) * (1.f / Dd) + 1e-5f);
  float rsc = rsqrtf(wredx(vc) * (1.f / Dd) + 1e-5f);

  float rg[8], rb[8], cg[8], cbb[8];
  *(float4*)&rg[0] = *(const float4*)(rn_g + d0);
  *(float4*)&rg[4] = *(const float4*)(rn_g + d0 + 4);
  *(float4*)&rb[0] = *(const float4*)(rn_b + d0);
  *(float4*)&rb[4] = *(const float4*)(rn_b + d0 + 4);
  *(float4*)&cg[0] = *(const float4*)(cn_g + d0);
  *(float4*)&cg[4] = *(const float4*)(cn_g + d0 + 4);
  *(float4*)&cbb[0] = *(const float4*)(cn_b + d0);
  *(float4*)&cbb[4] = *(const float4*)(cn_b + d0 + 4);

  float lg[Ee] = {0.f, 0.f, 0.f, 0.f, 0.f, 0.f, 0.f, 0.f};
#pragma unroll
  for (int d = 0; d < 8; d++) {
    float xn = (xv[d] - mx) * rsx * rg[d] + rb[d];
    float cn = (cv[d] - mc) * rsc * cg[d] + cbb[d];
    float rw[8], m1[8];
    *(float4*)&rw[0] = *(const float4*)(rtr_W + (size_t)(d0 + d) * Ee);
    *(float4*)&rw[4] = *(const float4*)(rtr_W + (size_t)(d0 + d) * Ee + 4);
    *(float4*)&m1[0] = *(const float4*)(M1 + (size_t)(d0 + d) * Ee);
    *(float4*)&m1[4] = *(const float4*)(M1 + (size_t)(d0 + d) * Ee + 4);
#pragma unroll
    for (int e = 0; e < Ee; e++) lg[e] += xn * rw[e] + cn * m1[e];
  }
#pragma unroll
  for (int e = 0; e < Ee; e++) lg[e] = wredx(lg[e]);

  if (lane == 0) {
    float invT = 1.f / fmaxf(temperature[0], 0.25f);
    float q = quality[t / Ss];
    float L[8];
#pragma unroll
    for (int e = 0; e < Ee; e++) L[e] = (lg[e] + q * qv[e] + cb[e]) * invT;
    *(float4*)(logitsS + (size_t)t * Ee) = *(float4*)&L[0];
    *(float4*)(logitsS + (size_t)t * Ee + 4) = *(float4*)&L[4];
  }
}

// ------------------------------------------------------------------
// Select: ONE block, top-2 + gates + stats + lists. No global atomics.
// ------------------------------------------------------------------
__global__ __launch_bounds__(256) void k_select(
    const float* __restrict__ logitsS, int* __restrict__ cnt,
    int* __restrict__ offs, int* __restrict__ list,
    float* __restrict__ glist, float* __restrict__ out) {
  __shared__ int scnt[Ee];
  __shared__ float s4[4];
  int tid = threadIdx.x;
  if (tid < Ee) scnt[tid] = 0;
  __syncthreads();

  float impL[Ee] = {0.f, 0.f, 0.f, 0.f, 0.f, 0.f, 0.f, 0.f};
  float zL = 0.f, eL = 0.f;

#pragma unroll
  for (int j = 0; j < 8; j++) {
    int t = j * 256 + tid;
    float L[8];
    *(float4*)&L[0] = *(const float4*)(logitsS + (size_t)t * Ee);
    *(float4*)&L[4] = *(const float4*)(logitsS + (size_t)t * Ee + 4);

    int i0 = 0;
#pragma unroll
    for (int e = 1; e < Ee; e++)
      if (L[e] > L[i0]) i0 = e;
    int i1 = (i0 == 0) ? 1 : 0;
#pragma unroll
    for (int e = 0; e < Ee; e++)
      if (e != i0 && L[e] > L[i1]) i1 = e;

    float e1 = __expf(L[i1] - L[i0]);
    float g0 = 1.f / (1.f + e1);
    float g1 = e1 / (1.f + e1);

    float m = L[i0];
    float p[8];
    float sum = 0.f;
#pragma unroll
    for (int e = 0; e < Ee; e++) {
      p[e] = __expf(L[e] - m);
      sum += p[e];
    }
    float lse = m + __logf(sum);
    float inv = 1.f / sum;
    zL += lse * lse;
#pragma unroll
    for (int e = 0; e < Ee; e++) {
      p[e] *= inv;
      eL -= p[e] * __logf(fmaxf(p[e], 1e-9f));
      impL[e] += p[e];
    }

    int s0 = atomicAdd(&scnt[i0], 1);
    list[i0 * CAP + s0] = t;
    glist[i0 * CAP + s0] = g0;
    int s1 = atomicAdd(&scnt[i1], 1);
    list[i1 * CAP + s1] = t;
    glist[i1 * CAP + s1] = g1;
  }

  float impS[Ee];
#pragma unroll
  for (int e = 0; e < Ee; e++) impS[e] = block_sum(impL[e], s4, tid);
  float zS = block_sum(zL, s4, tid);
  float eS = block_sum(eL, s4, tid);
  __syncthreads();

  if (tid == 0) {
    int s = 0;
#pragma unroll
    for (int e = 0; e < Ee; e++) {
      cnt[e] = scnt[e];
      offs[e] = s;
      s += scnt[e];
    }
    float lb = 0.f;
#pragma unroll
    for (int e = 0; e < Ee; e++) {
      float v = impS[e] * (1.f / TOKENS) - (1.f / Ee);
      lb += v * v;
    }
    lb *= (1.f / Ee);
    float rz = zS * (1.f / TOKENS);
    float en = eS * (1.f / TOKENS);
    float* sp = out + (size_t)Bb * Ss * Dd;
    sp[0] = lb;
    sp[1] = rz;
    sp[2] = en;
    sp[3] = lb + 0.001f * rz - 0.001f * en;
  }
}

// ------------------------------------------------------------------
// GEMM1 fp16: gathered X (ne x 512) @ W1[e] (512 x 2048), gelu -> hf
// 128x128 tile, BK=64, 4 waves (2x2), 32 MFMA/wave/step. grid: 8e x 16r x 16c
// ------------------------------------------------------------------
__global__ __launch_bounds__(256) void k_mg1(
    const _Float16* __restrict__ xf, const _Float16* __restrict__ w1f,
    const float* __restrict__ b1,
    const int* __restrict__ cnt, const int* __restrict__ offs,
    const int* __restrict__ list, _Float16* __restrict__ hf) {
  int bx = blockIdx.x;
  int e = bx >> 8;
  int r = (bx >> 4) & 15;
  int c = bx & 15;
  int ne = cnt[e];
  if (r * 128 >= ne) return;
  int off = offs[e];

  __shared__ _Float16 As[8 * 128 * 8];   // 16 KB  [g:8][row:128][8]
  __shared__ _Float16 Bs[8 * 128 * 8];   // 16 KB
  __shared__ int stok[128];

  int tid = threadIdx.x;
  if (tid < 128) {
    int row = r * 128 + tid;
    stok[tid] = list[e * CAP + ((row < ne) ? row : (ne - 1))];
  }
  __syncthreads();

  size_t asrc[4], bsrc[4];
  int lq[4];
#pragma unroll
  for (int q = 0; q < 4; q++) {
    int idx = q * 256 + tid;
    int g = idx >> 7, row = idx & 127;
    asrc[q] = (size_t)stok[row] * Dd + g * 8;
    bsrc[q] = ((size_t)(e * Hh + c * 128 + row)) * Dd + g * 8;
    lq[q] = idx * 8;
  }

  int lane = tid & 63, wid = tid >> 6;
  int wm = wid >> 1, wn = wid & 1;
  int l15 = lane & 15, lg = lane >> 4;

  f32x4 acc[4][4] = {};

  for (int k0 = 0; k0 < Dd; k0 += 64) {
#pragma unroll
    for (int q = 0; q < 4; q++) {
      GL16(xf + asrc[q] + k0, &As[lq[q]]);
      GL16(w1f + bsrc[q] + k0, &Bs[lq[q]]);
    }
    __syncthreads();
    f16x8 a[2][4], b[2][4];
#pragma unroll
    for (int ks = 0; ks < 2; ks++) {
#pragma unroll
      for (int m = 0; m < 4; m++)
        a[ks][m] = *(const f16x8*)&As[(((ks * 4 + lg) << 7) + wm * 64 + m * 16 + l15) * 8];
#pragma unroll
      for (int n = 0; n < 4; n++)
        b[ks][n] = *(const f16x8*)&Bs[(((ks * 4 + lg) << 7) + wn * 64 + n * 16 + l15) * 8];
    }
#pragma unroll
    for (int ks = 0; ks < 2; ks++)
#pragma unroll
      for (int m = 0; m < 4; m++)
#pragma unroll
        for (int n = 0; n < 4; n++)
          acc[m][n] = __builtin_amdgcn_mfma_f32_16x16x32_f16(a[ks][m], b[ks][n], acc[m][n], 0, 0, 0);
    __syncthreads();
  }

  int lg4 = lg * 4;
#pragma unroll
  for (int n = 0; n < 4; n++) {
    int colg = c * 128 + wn * 64 + n * 16 + l15;
    float bias = b1[e * Hh + colg];
#pragma unroll
    for (int m = 0; m < 4; m++) {
#pragma unroll
      for (int j = 0; j < 4; j++) {
        int rowl = r * 128 + wm * 64 + m * 16 + lg4 + j;
        if (rowl < ne)
          hf[(size_t)(off + rowl) * Hh + colg] = (_Float16)gelu_f(acc[m][n][j] + bias);
      }
    }
  }
}

// ------------------------------------------------------------------
// GEMM2 fp16: hf (ne x 2048) @ W2[e] (2048 x 512), +b2, gate, atomic scatter
// 128x128 tile, BK=64, split-K=4. grid: 8e x 16r x 4c x 4k
// ------------------------------------------------------------------
__global__ __launch_bounds__(256) void k_mg2(
    const _Float16* __restrict__ hf, const _Float16* __restrict__ w2f,
    const float* __restrict__ b2,
    const int* __restrict__ cnt, const int* __restrict__ offs,
    const int* __restrict__ list, const float* __restrict__ glist,
    float* __restrict__ out) {
  int bx = blockIdx.x;
  int e = bx >> 8;
  int r = (bx >> 4) & 15;
  int c = (bx >> 2) & 3;
  int kS = bx & 3;
  int ne = cnt[e];
  if (r * 128 >= ne) return;
  int off = offs[e];

  __shared__ _Float16 As[8 * 128 * 8];
  __shared__ _Float16 Bs[8 * 128 * 8];

  int tid = threadIdx.x;
  size_t kbase = (size_t)kS * 512;

  size_t asrc[4], bsrc[4];
  int lq[4];
#pragma unroll
  for (int q = 0; q < 4; q++) {
    int idx = q * 256 + tid;
    int g = idx >> 7, row = idx & 127;
    int ar = r * 128 + row;
    if (ar >= ne) ar = ne - 1;
    asrc[q] = (size_t)(off + ar) * Hh + kbase + g * 8;
    bsrc[q] = ((size_t)(e * Dd + c * 128 + row)) * Hh + kbase + g * 8;
    lq[q] = idx * 8;
  }

  int lane = tid & 63, wid = tid >> 6;
  int wm = wid >> 1, wn = wid & 1;
  int l15 = lane & 15, lg = lane >> 4;

  f32x4 acc[4][4] = {};

  for (int k0 = 0; k0 < 512; k0 += 64) {
#pragma unroll
    for (int q = 0; q < 4; q++) {
      GL16(hf + asrc[q] + k0, &As[lq[q]]);
      GL16(w2f + bsrc[q] + k0, &Bs[lq[q]]);
    }
    __syncthreads();
    f16x8 a[2][4], b[2][4];
#pragma unroll
    for (int ks = 0; ks < 2; ks++) {
#pragma unroll
      for (int m = 0; m < 4; m++)
        a[ks][m] = *(const f16x8*)&As[(((ks * 4 + lg) << 7) + wm * 64 + m * 16 + l15) * 8];
#pragma unroll
      for (int n = 0; n < 4; n++)
        b[ks][n] = *(const f16x8*)&Bs[(((ks * 4 + lg) << 7) + wn * 64 + n * 16 + l15) * 8];
    }
#pragma unroll
    for (int ks = 0; ks < 2; ks++)
#pragma unroll
      for (int m = 0; m < 4; m++)
#pragma unroll
        for (int n = 0; n < 4; n++)
          acc[m][n] = __builtin_amdgcn_mfma_f32_16x16x32_f16(a[ks][m], b[ks][n], acc[m][n], 0, 0, 0);
    __syncthreads();
  }

  int lg4 = lg * 4;
#pragma unroll
  for (int m = 0; m < 4; m++) {
#pragma unroll
    for (int j = 0; j < 4; j++) {
      int rowl = r * 128 + wm * 64 + m * 16 + lg4 + j;
      if (rowl < ne) {
        int tok = list[e * CAP + rowl];
        float gte = glist[e * CAP + rowl];
#pragma unroll
        for (int n = 0; n < 4; n++) {
          int colg = c * 128 + wn * 64 + n * 16 + l15;
          float v = acc[m][n][j] + (kS == 0 ? b2[e * Dd + colg] : 0.f);
          atomicAdd(&out[(size_t)tok * Dd + colg], gte * v);
        }
      }
    }
  }
}

extern "C" void kernel_launch(void* const* d_in, const int* in_sizes, int n_in,
                              void* d_out, int out_size, void* d_ws, size_t ws_size,
                              hipStream_t stream) {
  const float* x = (const float*)d_in[0];
  const float* ctx = (const float*)d_in[1];
  const float* quality = (const float*)d_in[2];
  const float* rn_g = (const float*)d_in[3];
  const float* rn_b = (const float*)d_in[4];
  const float* cn_g = (const float*)d_in[5];
  const float* cn_b = (const float*)d_in[6];
  const float* ctx_W = (const float*)d_in[7];
  const float* ctx_b = (const float*)d_in[8];
  const float* qual_W = (const float*)d_in[9];
  const float* qual_b = (const float*)d_in[10];
  const float* rtr_W = (const float*)d_in[11];
  const float* rtr_b = (const float*)d_in[12];
  const float* temperature = (const float*)d_in[13];
  const float* W1 = (const float*)d_in[14];
  const float* b1 = (const float*)d_in[15];
  const float* W2 = (const float*)d_in[16];
  const float* b2 = (const float*)d_in[17];
  float* out = (float*)d_out;

  char* w = (char*)d_ws;
  int* cnt = (int*)(w + WS_CNT);
  int* offs = (int*)(w + WS_OFFS);
  float* M1 = (float*)(w + WS_M1);
  float* qv = (float*)(w + WS_QV);
  float* cb = (float*)(w + WS_CB);
  int* list = (int*)(w + WS_LIST);
  float* glist = (float*)(w + WS_GLIST);
  float* logitsS = (float*)(w + WS_LOG);
  _Float16* xf = (_Float16*)(w + WS_XF);
  _Float16* w1f = (_Float16*)(w + WS_W1F);
  _Float16* w2f = (_Float16*)(w + WS_W2F);
  _Float16* hf = (_Float16*)(w + WS_HF);

  hipMemsetAsync(d_out, 0, (size_t)out_size * sizeof(float), stream);

  k_pre<<<513 + Ee * 8 * 32 * 2, 256, 0, stream>>>(
      ctx_W, rtr_W, rtr_b, qual_W, qual_b, ctx_b, W1, W2, M1, qv, cb, w1f, w2f);
  k_logits<<<TOKENS / 4, 256, 0, stream>>>(x, ctx, quality, rn_g, rn_b, cn_g, cn_b, rtr_W,
                                           M1, qv, cb, temperature, logitsS, xf);
  k_select<<<1, 256, 0, stream>>>(logitsS, cnt, offs, list, glist, out);
  k_mg1<<<Ee * 16 * 16, 256, 0, stream>>>(xf, w1f, b1, cnt, offs, list, hf);
  k_mg2<<<Ee * 16 * 4 * 4, 256, 0, stream>>>(hf, w2f, b2, cnt, offs, list, glist, out);
}